// Round 6
// baseline (1263.628 us; speedup 1.0000x reference)
//
#include <hip/hip_runtime.h>
#include <hip/hip_bf16.h>
#include <stdint.h>

#define NF 256
#define EPSV 1e-5f
#define PB 160     // max bn partial blocks
#define MAXBUK 160 // max coarse buckets (dst>>8): 157 for NT=40000
// s_getreg imm for HW_REG_XCC_ID (id=20, offset=0, size=4): ((4-1)<<11)|20
#define XCCID_IMM 6164

typedef unsigned short u16;
typedef unsigned int u32;
typedef short short8 __attribute__((ext_vector_type(8)));
typedef float floatx4 __attribute__((ext_vector_type(4)));

// param block offsets (floats): 12 x 256, then 6 x 512, then 2 x 1
#define P_BGCN 0
#define P_G1 256
#define P_BE1 512
#define P_BAGG 768
#define P_AGG1 1024
#define P_AGBE1 1280
#define P_ASRC 1536
#define P_ADST 1792
#define P_BGAT 2048
#define P_ASRC2 2304
#define P_ADST2 2560
#define P_BGAT2 2816
#define P_G2 3072
#define P_BE2 3584
#define P_WFC 4096
#define P_AGG2 4608
#define P_AGBE2 5120
#define P_WAGFC 5632
#define P_BFC 6144
#define P_BAGFC 6145

__device__ __forceinline__ float bf2f(u16 u) {
    union { unsigned int i; float f; } v; v.i = ((unsigned int)u) << 16; return v.f;
}
__device__ __forceinline__ u16 f2bf(float f) {
    unsigned int x = __float_as_uint(f);
    unsigned int r = x + 0x7fffu + ((x >> 16) & 1u);
    return (u16)(r >> 16);
}
__device__ __forceinline__ float sane(float f) {
    return (f == f && fabsf(f) < 1e30f) ? f : 0.f;
}
__device__ __forceinline__ unsigned int zap2(unsigned int w) {
    if ((w & 0x00007F80u) == 0x00007F80u) w &= 0xFFFF0000u;
    if ((w & 0x7F800000u) == 0x7F800000u) w &= 0x0000FFFFu;
    return w;
}
__device__ __forceinline__ float lrelu(float x) { return x > 0.f ? x : 0.2f * x; }

// 4 bf16 (uint2) -> acc[k] += a * h[k]
__device__ __forceinline__ void fma4u(const uint2 u, float a, float* acc) {
    acc[0] = fmaf(__uint_as_float(u.x << 16), a, acc[0]);
    acc[1] = fmaf(__uint_as_float(u.x & 0xFFFF0000u), a, acc[1]);
    acc[2] = fmaf(__uint_as_float(u.y << 16), a, acc[2]);
    acc[3] = fmaf(__uint_as_float(u.y & 0xFFFF0000u), a, acc[3]);
}
__device__ __forceinline__ void st4hp(u16* p, const float* v) {
    uint2 u;
    u.x = (u32)f2bf(v[0]) | ((u32)f2bf(v[1]) << 16);
    u.y = (u32)f2bf(v[2]) | ((u32)f2bf(v[3]) << 16);
    *(uint2*)p = u;
}
__device__ __forceinline__ void st8h(u16* p, const float* v) {
    uint4 u;
    u.x = (u32)f2bf(v[0]) | ((u32)f2bf(v[1]) << 16);
    u.y = (u32)f2bf(v[2]) | ((u32)f2bf(v[3]) << 16);
    u.z = (u32)f2bf(v[4]) | ((u32)f2bf(v[5]) << 16);
    u.w = (u32)f2bf(v[6]) | ((u32)f2bf(v[7]) << 16);
    *(uint4*)p = u;
}

__device__ __forceinline__ float wredsum(float v) {
#pragma unroll
    for (int o = 32; o > 0; o >>= 1) v += __shfl_xor(v, o, 64);
    return v;
}
__device__ __forceinline__ int wscan_incl(int x, int lane) {
#pragma unroll
    for (int o = 1; o < 64; o <<= 1) {
        int t = __shfl_up(x, o, 64);
        if (lane >= o) x += t;
    }
    return x;
}

// ---------------- dtype detect ----------------
__global__ void detect_k(const u16* __restrict__ x, int* __restrict__ flag) {
    __shared__ int cnt;
    if (threadIdx.x == 0) cnt = 0;
    __syncthreads();
    int c = 0;
#pragma unroll
    for (int k = 0; k < 4; ++k) {
        unsigned int u = x[2 * (threadIdx.x + 256 * k)];
        int e = (int)((u >> 7) & 0xFFu);
        if (u == 0u || (e >= 100 && e <= 140)) c++;
    }
    atomicAdd(&cnt, c);
    __syncthreads();
    if (threadIdx.x == 0) flag[0] = (cnt >= 512) ? 1 : 0;
}

// ---------------- prep: weight fragment-pack + param cvt + counter zero ----------------
__global__ void prep_k(const void* w0, const void* w1, const void* w2, const void* w3,
                       const void* p0, const void* p1, const void* p2, const void* p3,
                       const void* p4, const void* p5, const void* p6, const void* p7,
                       const void* p8, const void* p9, const void* p10, const void* p11,
                       const void* p12, const void* p13, const void* p14, const void* p15,
                       const void* p16, const void* p17, const void* p18, const void* p19,
                       u16* __restrict__ wtf, float* __restrict__ prm,
                       int* __restrict__ zb, int nz,
                       const int* __restrict__ flagp) {
    int f = flagp[0];
    int idx = blockIdx.x * 256 + threadIdx.x;
    if (idx < nz) zb[idx] = 0;
    if (idx < 262144) {
        const void* ws[4] = {w0, w1, w2, w3};
        int wi = idx >> 16;
        int rest = idx & 65535;
        int j = rest & 7;
        int lr = (rest >> 3) & 15;
        int q = (rest >> 7) & 3;
        int nf = (rest >> 9) & 15;
        int ks = (rest >> 13) & 7;
        int n = nf * 16 + lr;
        int k = ks * 32 + q * 8 + j;
        const void* W = ws[wi];
        u16 v;
        if (f) {
            v = ((const u16*)W)[k * NF + n];
            if ((v & 0x7F80u) == 0x7F80u) v = 0;
        } else {
            v = f2bf(sane(((const float*)W)[k * NF + n]));
        }
        wtf[idx] = v;
        return;
    }
    int pidx = idx - 262144;
    if (pidx >= 6146) return;
    const void* ptrs[20] = {p0, p1, p2, p3, p4, p5, p6, p7, p8, p9,
                            p10, p11, p12, p13, p14, p15, p16, p17, p18, p19};
    int t, j;
    if (pidx < 3072) { t = pidx >> 8; j = pidx & 255; }
    else if (pidx < 6144) { t = 12 + ((pidx - 3072) >> 9); j = (pidx - 3072) & 511; }
    else { t = 18 + (pidx - 6144); j = 0; }
    float v = f ? bf2f(((const u16*)ptrs[t])[j]) : ((const float*)ptrs[t])[j];
    prm[pidx] = sane(v);
}

// ---------------- bucket-level CSR build (y = graph: 0=ab, 1=ag, 2=d) ----------------
__global__ __launch_bounds__(256) void bucket_cnt3_k(const int* e0, const int* e1,
                                                     const int* e2,
                                                     int* __restrict__ gbcnt) {
    int y = blockIdx.y;
    const int* ei = (y == 0) ? e0 : (y == 1) ? e1 : e2;
    int E = (y == 2) ? 640000 : 320000;
    int n = (y == 2) ? 40000 : 20000;
    int nbuk = (n + 255) >> 8;
    int base = blockIdx.x * 4096;
    if (base >= E) return;
    __shared__ int l[MAXBUK];
    if (threadIdx.x < nbuk) l[threadIdx.x] = 0;
    __syncthreads();
#pragma unroll
    for (int t = 0; t < 16; ++t) {
        int e = base + t * 256 + threadIdx.x;
        if (e < E) atomicAdd(&l[ei[E + e] >> 8], 1);
    }
    __syncthreads();
    if (threadIdx.x < nbuk) {
        int c = l[threadIdx.x];
        if (c) atomicAdd(&gbcnt[y * MAXBUK + threadIdx.x], c);
    }
}
__global__ __launch_bounds__(256) void bucket_scan3_k(const int* __restrict__ gbcnt,
                                                      int* __restrict__ bb,
                                                      int* rp0, int* rp1, int* rp2) {
    __shared__ int wp[4];
    int y = blockIdx.y;
    int n = (y == 2) ? 40000 : 20000;
    int E = (y == 2) ? 640000 : 320000;
    int nbuk = (n + 255) >> 8;
    int* rp = (y == 0) ? rp0 : (y == 1) ? rp1 : rp2;
    int lane = threadIdx.x & 63, wave = threadIdx.x >> 6;
    int v = (threadIdx.x < nbuk) ? gbcnt[y * MAXBUK + threadIdx.x] : 0;
    int x = wscan_incl(v, lane);
    if (lane == 63) wp[wave] = x;
    __syncthreads();
    int off = 0;
#pragma unroll
    for (int w = 0; w < 4; ++w) off += (w < wave) ? wp[w] : 0;
    if (threadIdx.x < nbuk) bb[y * (MAXBUK + 1) + threadIdx.x] = off + x - v;
    if (threadIdx.x == 0) {
        bb[y * (MAXBUK + 1) + nbuk] = E;
        rp[n] = E;
    }
}
__global__ __launch_bounds__(256) void bin3_k(const int* e0, const int* e1, const int* e2,
                                              const int* __restrict__ bb,
                                              int* __restrict__ gcur,
                                              u32* s0, u32* s1, u32* s2) {
    int y = blockIdx.y;
    const int* ei = (y == 0) ? e0 : (y == 1) ? e1 : e2;
    u32* stg = (y == 0) ? s0 : (y == 1) ? s1 : s2;
    int E = (y == 2) ? 640000 : 320000;
    int n = (y == 2) ? 40000 : 20000;
    int nbuk = (n + 255) >> 8;
    int base = blockIdx.x * 4096;
    if (base >= E) return;
    __shared__ int lcnt[MAXBUK];
    __shared__ int lbase[MAXBUK];
    if (threadIdx.x < nbuk) lcnt[threadIdx.x] = 0;
    __syncthreads();
#pragma unroll
    for (int t = 0; t < 16; ++t) {
        int e = base + t * 256 + threadIdx.x;
        if (e < E) atomicAdd(&lcnt[ei[E + e] >> 8], 1);
    }
    __syncthreads();
    if (threadIdx.x < nbuk) {
        int cnt = lcnt[threadIdx.x];
        int g = cnt ? atomicAdd(&gcur[y * MAXBUK + threadIdx.x], cnt) : 0;
        lbase[threadIdx.x] = bb[y * (MAXBUK + 1) + threadIdx.x] + g;
        lcnt[threadIdx.x] = 0;
    }
    __syncthreads();
#pragma unroll
    for (int t = 0; t < 16; ++t) {
        int e = base + t * 256 + threadIdx.x;
        if (e < E) {
            int s = ei[e], d = ei[E + e];
            int b = d >> 8;
            int r = atomicAdd(&lcnt[b], 1);
            stg[lbase[b] + r] = (u32)s | ((u32)(d & 255) << 16);
        }
    }
}
__global__ __launch_bounds__(256) void place3_k(const u32* s0, const u32* s1, const u32* s2,
                                                const int* __restrict__ bb,
                                                int* rp0, int* rp1, int* rp2,
                                                float* dv0, float* dv1,
                                                int* c0, int* c1, int* c2) {
    __shared__ int wp[4];
    __shared__ int lcnt[256];
    __shared__ int lrp[256];
    int y = blockIdx.y;
    int b = blockIdx.x;
    int n = (y == 2) ? 40000 : 20000;
    int nbuk = (n + 255) >> 8;
    if (b >= nbuk) return;
    const u32* stg = (y == 0) ? s0 : (y == 1) ? s1 : s2;
    int* rp = (y == 0) ? rp0 : (y == 1) ? rp1 : rp2;
    int* col = (y == 0) ? c0 : (y == 1) ? c1 : c2;
    int d0 = b << 8;
    int dn = min(256, n - d0);
    int base = bb[y * (MAXBUK + 1) + b];
    int endv = bb[y * (MAXBUK + 1) + b + 1];
    lcnt[threadIdx.x] = 0;
    __syncthreads();
    for (int j = base + threadIdx.x; j < endv; j += 256)
        atomicAdd(&lcnt[stg[j] >> 16], 1);
    __syncthreads();
    int lane = threadIdx.x & 63, wave = threadIdx.x >> 6;
    int v = lcnt[threadIdx.x];
    int x = wscan_incl(v, lane);
    if (lane == 63) wp[wave] = x;
    __syncthreads();
    int off = 0;
#pragma unroll
    for (int w = 0; w < 4; ++w) off += (w < wave) ? wp[w] : 0;
    int excl = base + off + x - v;
    lrp[threadIdx.x] = excl;
    if (threadIdx.x < dn) {
        rp[d0 + threadIdx.x] = excl;
        if (y == 0) dv0[d0 + threadIdx.x] = rsqrtf((float)(v + 1));
        else if (y == 1) dv1[d0 + threadIdx.x] = rsqrtf((float)(v + 1));
    }
    lcnt[threadIdx.x] = 0;
    __syncthreads();
    for (int j = base + threadIdx.x; j < endv; j += 256) {
        u32 rec = stg[j];
        int dl = (int)(rec >> 16);
        int s = (int)(rec & 0xFFFFu);
        int r = atomicAdd(&lcnt[dl], 1);
        col[lrp[dl] + r] = s;
    }
}

// ---------------- batched GCN GEMM (y = graph), slab-major C output ----------
// C layout: 8 slabs of [M][32] bf16 per graph (slab = channel>>5).
__global__ __launch_bounds__(256) void gemm2_k(const void* A0, const void* A1,
                                               const u16* __restrict__ Wtf0,
                                               const u16* __restrict__ Wtf1,
                                               const int* __restrict__ flagp,
                                               u16* __restrict__ C, int M) {
    int f = flagp[0];
    int y = blockIdx.y;
    const void* Aptr = y ? A1 : A0;
    const u16* Wtf = y ? Wtf1 : Wtf0;
    u16* Cp = C + (size_t)y * M * NF;
    int wave = threadIdx.x >> 6, lane = threadIdx.x & 63;
    int lr = lane & 15, q = lane >> 4;
    int arow = blockIdx.x * 64 + wave * 16 + lr;
    bool rok = arow < M;
    floatx4 acc[16];
#pragma unroll
    for (int nf = 0; nf < 16; ++nf) acc[nf] = (floatx4){0.f, 0.f, 0.f, 0.f};
    const u16* a16 = (const u16*)Aptr + (size_t)arow * NF;
    const float* a32 = (const float*)Aptr + (size_t)arow * NF;
#pragma unroll
    for (int ks = 0; ks < 8; ++ks) {
        int kk = ks * 32 + q * 8;
        union { u16 s[8]; uint4 u; short8 v; } a;
        if (!rok) {
            a.u = make_uint4(0u, 0u, 0u, 0u);
        } else if (f) {
            a.u = *(const uint4*)(a16 + kk);
            a.u.x = zap2(a.u.x); a.u.y = zap2(a.u.y);
            a.u.z = zap2(a.u.z); a.u.w = zap2(a.u.w);
        } else {
            float4 f0 = *(const float4*)(a32 + kk);
            float4 f1 = *(const float4*)(a32 + kk + 4);
            a.s[0] = f2bf(sane(f0.x)); a.s[1] = f2bf(sane(f0.y));
            a.s[2] = f2bf(sane(f0.z)); a.s[3] = f2bf(sane(f0.w));
            a.s[4] = f2bf(sane(f1.x)); a.s[5] = f2bf(sane(f1.y));
            a.s[6] = f2bf(sane(f1.z)); a.s[7] = f2bf(sane(f1.w));
        }
        const u16* bbase = Wtf + ks * 8192 + lane * 8;
#pragma unroll
        for (int nf = 0; nf < 16; ++nf) {
            short8 b = *(const short8*)(bbase + nf * 512);
            acc[nf] = __builtin_amdgcn_mfma_f32_16x16x32_bf16(a.v, b, acc[nf], 0, 0, 0);
        }
    }
#pragma unroll
    for (int nf = 0; nf < 16; ++nf) {
        int colb = nf * 16 + lr;
        u16* dst = Cp + (size_t)(colb >> 5) * M * 32 + (colb & 31);
#pragma unroll
        for (int rr = 0; rr < 4; ++rr) {
            int gr = blockIdx.x * 64 + wave * 16 + q * 4 + rr;
            if (gr < M) dst[(size_t)gr * 32] = f2bf(acc[nf][rr]);
        }
    }
}

// ---------------- GAT GEMM MR=1, slab-major C, fused scores epilogue ----------------
__global__ __launch_bounds__(256) void gemm_gat_k(const u16* __restrict__ Aptr,
                                                  const u16* __restrict__ Wtf,
                                                  u16* __restrict__ C, int M,
                                                  const float* __restrict__ as_,
                                                  const float* __restrict__ ad_,
                                                  float* __restrict__ es,
                                                  float* __restrict__ ed) {
    int wave = threadIdx.x >> 6, lane = threadIdx.x & 63;
    int lr = lane & 15, q = lane >> 4;
    int arow = blockIdx.x * 64 + wave * 16 + lr;
    bool rok = arow < M;
    floatx4 acc[16];
#pragma unroll
    for (int nf = 0; nf < 16; ++nf) acc[nf] = (floatx4){0.f, 0.f, 0.f, 0.f};
    const u16* a16 = Aptr + (size_t)arow * NF;
#pragma unroll
    for (int ks = 0; ks < 8; ++ks) {
        int kk = ks * 32 + q * 8;
        union { uint4 u; short8 v; } a;
        a.u = rok ? *(const uint4*)(a16 + kk) : make_uint4(0u, 0u, 0u, 0u);
        const u16* bbase = Wtf + ks * 8192 + lane * 8;
#pragma unroll
        for (int nf = 0; nf < 16; ++nf) {
            short8 b = *(const short8*)(bbase + nf * 512);
            acc[nf] = __builtin_amdgcn_mfma_f32_16x16x32_bf16(a.v, b, acc[nf], 0, 0, 0);
        }
    }
#pragma unroll
    for (int nf = 0; nf < 16; ++nf) {
        int colb = nf * 16 + lr;
        u16* dst = C + (size_t)(colb >> 5) * M * 32 + (colb & 31);
#pragma unroll
        for (int rr = 0; rr < 4; ++rr) {
            int gr = blockIdx.x * 64 + wave * 16 + q * 4 + rr;
            if (gr < M) dst[(size_t)gr * 32] = f2bf(acc[nf][rr]);
        }
    }
    float asl[16], adl[16];
#pragma unroll
    for (int nf = 0; nf < 16; ++nf) { asl[nf] = as_[nf * 16 + lr]; adl[nf] = ad_[nf * 16 + lr]; }
#pragma unroll
    for (int rr = 0; rr < 4; ++rr) {
        float s1 = 0.f, s2 = 0.f;
#pragma unroll
        for (int nf = 0; nf < 16; ++nf) {
            s1 += acc[nf][rr] * asl[nf];
            s2 += acc[nf][rr] * adl[nf];
        }
#pragma unroll
        for (int o = 1; o < 16; o <<= 1) {
            s1 += __shfl_xor(s1, o, 64);
            s2 += __shfl_xor(s2, o, 64);
        }
        int gr = blockIdx.x * 64 + wave * 16 + q * 4 + rr;
        if (lr == 0 && gr < M) { es[gr] = s1; ed[gr] = s2; }
    }
}

// ---------------- XCC-pinned GCN aggregation (slab-major h input) ----------------
// Each XCD drains the ticket queue of its own 32-ch slab (1.28MB/graph, L2-resident),
// then steals from other slabs' queues (correct under any XCD mapping).
// Wave: 8 edge-slots x 8 lanes; lane covers 4 ch (uint2). Ticket = 64 dsts.
__global__ __launch_bounds__(256) void gcn_csr2_k(const u16* __restrict__ h,
                                                  const int* rp0, const int* rp1,
                                                  const int* c0, const int* c1,
                                                  const float* dv0, const float* dv1,
                                                  const float* __restrict__ prm,
                                                  u16* __restrict__ out, int n,
                                                  int* __restrict__ wq) {
    __shared__ int ls;
    int wave = threadIdx.x >> 6, lane = threadIdx.x & 63;
    int egrp = lane >> 3, cl = (lane & 7) * 4;
    int xcd = __builtin_amdgcn_s_getreg(XCCID_IMM) & 7;
    for (int d = 0; d < 8; ++d) {
        int slab = (xcd + d) & 7;
        for (int it = 0; it < 4096; ++it) {   // bounded (defensive; never hit)
            if (threadIdx.x == 0) ls = atomicAdd(&wq[slab], 1);
            __syncthreads();
            int t = ls;
            __syncthreads();
            if (t >= 626) break;
            int y = t >= 313;
            int base = (t - y * 313) * 64 + wave * 16;
            const int* rp = y ? rp1 : rp0;
            const int* col = y ? c1 : c0;
            const float* dinv = y ? dv1 : dv0;
            const float* b = prm + (y ? P_BAGG : P_BGCN) + slab * 32;
            const u16* hs = h + (size_t)y * n * NF + (size_t)slab * n * 32;
            u16* ob = out + (size_t)y * n * NF;
            for (int tt = 0; tt < 16; ++tt) {
                int i = base + tt;
                if (i >= n) break;
                int beg = rp[i], end = rp[i + 1];
                float di = dinv[i];
                float selfw = (egrp == 0) ? di * di : 0.f;
                uint2 us = *(const uint2*)(hs + (size_t)i * 32 + cl);
                float acc[4] = {0.f, 0.f, 0.f, 0.f};
                fma4u(us, selfw, acc);
                for (int j = beg; j < end; j += 8) {
                    int e = j + egrp;
                    bool v = e < end;
                    int s = v ? col[e] : i;
                    float a = v ? dinv[s] * di : 0.f;
                    uint2 u = *(const uint2*)(hs + (size_t)s * 32 + cl);
                    fma4u(u, a, acc);
                }
#pragma unroll
                for (int o = 8; o < 64; o <<= 1) {
#pragma unroll
                    for (int k = 0; k < 4; ++k) acc[k] += __shfl_xor(acc[k], o, 64);
                }
                if (egrp == 0) {
                    float r[4];
#pragma unroll
                    for (int k = 0; k < 4; ++k) r[k] = acc[k] + b[cl + k];
                    st4hp(ob + (size_t)i * NF + slab * 32 + cl, r);
                }
            }
        }
    }
}

// ---------------- BN partial stats (no atomics) ----------------
__global__ void bn_stats2_k(const u16* __restrict__ x, int n,
                            float* __restrict__ psum, float* __restrict__ psq) {
    int y = blockIdx.y;
    int c = threadIdx.x;  // 256
    int r0 = blockIdx.x * 128;
    int rend = min(r0 + 128, n);
    const u16* xb = x + (size_t)y * n * NF;
    float s = 0.f, qq = 0.f;
    for (int r = r0; r < rend; ++r) {
        float v = bf2f(xb[(size_t)r * NF + c]);
        s += v; qq += v * v;
    }
    size_t o = (size_t)(y * PB + blockIdx.x) * 512 + c;
    psum[o] = s; psq[o] = qq;
}
// wave-per-channel finalize
__global__ void bn_fin2_k(const float* __restrict__ psum, const float* __restrict__ psq,
                          float* __restrict__ stg, int n, int nb) {
    int y = blockIdx.y;
    int wave = threadIdx.x >> 6, lane = threadIdx.x & 63;
    int c = blockIdx.x * 4 + wave;   // 256 channels, grid.x = 64
    float s = 0.f, qq = 0.f;
    for (int b = lane; b < nb; b += 64) {
        size_t o = (size_t)(y * PB + b) * 512 + c;
        s += psum[o]; qq += psq[o];
    }
    s = wredsum(s);
    qq = wredsum(qq);
    if (lane == 0) {
        float inv_n = 1.0f / (float)n;
        float mean = s * inv_n;
        float var = fmaxf(qq * inv_n - mean * mean, 0.f);
        stg[y * 512 + c] = mean;
        stg[y * 512 + 256 + c] = rsqrtf(var + EPSV);
    }
}
// vectorized: 8 values per thread (uint4 in / uint4 out)
__global__ void bn_apply2_k(const u16* __restrict__ x, const float* __restrict__ stg,
                            const float* __restrict__ prm, u16* __restrict__ out, int n) {
    int y = blockIdx.y;
    int t = blockIdx.x * 256 + threadIdx.x;
    if (t >= n * (NF / 8)) return;
    int c = (t & 31) * 8;
    const float* st = stg + y * 512;
    const float* g = prm + (y ? P_AGG1 : P_G1);
    const float* be = prm + (y ? P_AGBE1 : P_BE1);
    uint4 u = *(const uint4*)(x + (size_t)y * n * NF + (size_t)t * 8);
    float v[8];
    v[0] = __uint_as_float(u.x << 16); v[1] = __uint_as_float(u.x & 0xFFFF0000u);
    v[2] = __uint_as_float(u.y << 16); v[3] = __uint_as_float(u.y & 0xFFFF0000u);
    v[4] = __uint_as_float(u.z << 16); v[5] = __uint_as_float(u.z & 0xFFFF0000u);
    v[6] = __uint_as_float(u.w << 16); v[7] = __uint_as_float(u.w & 0xFFFF0000u);
    float r[8];
#pragma unroll
    for (int k = 0; k < 8; ++k) {
        int cc = c + k;
        float w = (v[k] - st[cc]) * st[256 + cc] * g[cc] + be[cc];
        r[k] = fmaxf(w, 0.f);
    }
    st8h(out + (size_t)y * n * NF + (size_t)t * 8, r);
}

// ---------------- XCC-pinned fused GAT aggregation (slab-major h input) ----------------
__global__ __launch_bounds__(256) void gat_csr_k(const u16* __restrict__ h,
                                                 const int* __restrict__ rp,
                                                 const int* __restrict__ col,
                                                 const float* __restrict__ es,
                                                 const float* __restrict__ ed,
                                                 const float* __restrict__ b,
                                                 u16* __restrict__ out, int n,
                                                 int do_relu, int* __restrict__ wq) {
    __shared__ int ls;
    int wave = threadIdx.x >> 6, lane = threadIdx.x & 63;
    int egrp = lane >> 3, cl = (lane & 7) * 4;
    int xcd = __builtin_amdgcn_s_getreg(XCCID_IMM) & 7;
    for (int d = 0; d < 8; ++d) {
        int slab = (xcd + d) & 7;
        const u16* hs = h + (size_t)slab * n * 32;
        const float* bs = b + slab * 32;
        for (int it = 0; it < 4096; ++it) {   // bounded (defensive; never hit)
            if (threadIdx.x == 0) ls = atomicAdd(&wq[slab], 1);
            __syncthreads();
            int t = ls;
            __syncthreads();
            if (t >= 625) break;
            int base = t * 64 + wave * 16;
            for (int tt = 0; tt < 16; ++tt) {
                int i = base + tt;
                if (i >= n) break;
                int beg = rp[i], end = rp[i + 1];
                float edi = ed[i];
                float ws = __expf(lrelu(es[i] + edi));
                float selfw = (egrp == 0) ? ws : 0.f;
                float ssum = selfw;
                uint2 us = *(const uint2*)(hs + (size_t)i * 32 + cl);
                float acc[4] = {0.f, 0.f, 0.f, 0.f};
                fma4u(us, selfw, acc);
                for (int j = beg; j < end; j += 8) {
                    int e = j + egrp;
                    bool v = e < end;
                    int s = v ? col[e] : i;
                    float a = v ? __expf(lrelu(es[s] + edi)) : 0.f;
                    uint2 u = *(const uint2*)(hs + (size_t)s * 32 + cl);
                    ssum += a;
                    fma4u(u, a, acc);
                }
#pragma unroll
                for (int o = 8; o < 64; o <<= 1) {
                    ssum += __shfl_xor(ssum, o, 64);
#pragma unroll
                    for (int k = 0; k < 4; ++k) acc[k] += __shfl_xor(acc[k], o, 64);
                }
                if (egrp == 0) {
                    float inv = 1.0f / ssum;
                    float r[4];
#pragma unroll
                    for (int k = 0; k < 4; ++k) {
                        r[k] = bs[cl + k] + acc[k] * inv;
                        if (do_relu) r[k] = fmaxf(r[k], 0.f);
                    }
                    st4hp(out + (size_t)i * NF + slab * 32 + cl, r);
                }
            }
        }
    }
}

// ---------------- batched final-stage BN stats over cat(x,h) (512 ch) ----------------
__global__ void bn_stats_cat2_k(const u16* __restrict__ xp, const u16* __restrict__ hp,
                                int n, float* __restrict__ psum, float* __restrict__ psq) {
    int y = blockIdx.y;
    int c = threadIdx.x;  // 512
    int r0 = blockIdx.x * 128;
    int rend = min(r0 + 128, n);
    const u16* src = ((c < 256) ? xp : hp) + (size_t)y * n * NF;
    int cc = c & 255;
    float s = 0.f, qq = 0.f;
    for (int r = r0; r < rend; ++r) {
        float v = bf2f(src[(size_t)r * NF + cc]);
        s += v; qq += v * v;
    }
    size_t o = (size_t)(y * PB + blockIdx.x) * 512 + c;
    psum[o] = s; psq[o] = qq;
}
// wave-per-channel finalize (512 channels)
__global__ void bn_fin_cat2_k(const float* __restrict__ psum, const float* __restrict__ psq,
                              float* __restrict__ stc, int n, int nb) {
    int y = blockIdx.y;
    int wave = threadIdx.x >> 6, lane = threadIdx.x & 63;
    int c = blockIdx.x * 4 + wave;   // 512 channels, grid.x = 128
    float s = 0.f, qq = 0.f;
    for (int b = lane; b < nb; b += 64) {
        size_t o = (size_t)(y * PB + b) * 512 + c;
        s += psum[o]; qq += psq[o];
    }
    s = wredsum(s);
    qq = wredsum(qq);
    if (lane == 0) {
        float inv_n = 1.0f / (float)n;
        float mean = s * inv_n;
        float var = fmaxf(qq * inv_n - mean * mean, 0.f);
        stc[y * 1024 + c] = mean;
        stc[y * 1024 + 512 + c] = rsqrtf(var + EPSV);
    }
}
__global__ void final2_k(const u16* __restrict__ xp, const u16* __restrict__ hp,
                         const float* __restrict__ stc, const float* __restrict__ prm,
                         float* __restrict__ out, int n) {
    int y = blockIdx.y;
    int wave = threadIdx.x >> 6, lane = threadIdx.x & 63;
    int i = blockIdx.x * 4 + wave;
    if (i >= n) return;
    const float* st = stc + y * 1024;
    const float* g = prm + (y ? P_AGG2 : P_G2);
    const float* be = prm + (y ? P_AGBE2 : P_BE2);
    const float* w = prm + (y ? P_WAGFC : P_WFC);
    float bias = prm[y ? P_BAGFC : P_BFC];
    const u16* src = (((lane < 32) ? xp : hp) + (size_t)y * n * NF) + (size_t)i * NF
                     + (lane < 32 ? lane * 8 : (lane - 32) * 8);
    uint4 u = *(const uint4*)src;
    float vv[8];
    vv[0] = bf2f((u16)(u.x & 0xFFFFu)); vv[1] = bf2f((u16)(u.x >> 16));
    vv[2] = bf2f((u16)(u.y & 0xFFFFu)); vv[3] = bf2f((u16)(u.y >> 16));
    vv[4] = bf2f((u16)(u.z & 0xFFFFu)); vv[5] = bf2f((u16)(u.z >> 16));
    vv[6] = bf2f((u16)(u.w & 0xFFFFu)); vv[7] = bf2f((u16)(u.w >> 16));
    int c0 = lane * 8;
    float acc = 0.f;
#pragma unroll
    for (int j = 0; j < 8; ++j) {
        int c = c0 + j;
        float v = (vv[j] - st[c]) * st[512 + c] * g[c] + be[c];
        v = fmaxf(v, 0.f);
        acc += v * w[c];
    }
    acc = wredsum(acc);
    if (lane == 0) out[(size_t)y * 20000 + i] = acc + bias;
}

// ---------------- host ----------------
extern "C" void kernel_launch(void* const* d_in, const int* in_sizes, int n_in,
                              void* d_out, int out_size, void* d_ws, size_t ws_size,
                              hipStream_t stream) {
    const void* x_ab = d_in[0];
    const void* x_ag = d_in[1];
    const int* e_ab = (const int*)d_in[26];
    const int* e_ag = (const int*)d_in[27];
    const int* e_d = (const int*)d_in[28];

    const int NAB = 20000, NT = 40000;
    const int EAB = 320000, EAG = 320000, ED = 640000;

    u16* hcat = (u16*)d_ws;                     // NT*NF u16
    u16* bufA = hcat + (size_t)NT * NF;         // NT*NF u16
    u16* bufB = bufA + (size_t)NT * NF;         // NT*NF u16
    u16* wt4 = bufB + (size_t)NT * NF;          // 4*65536 u16
    float* dv0 = (float*)(wt4 + 4 * 65536);     // NAB
    float* dv1 = dv0 + NAB;                     // NAB
    float* es = dv1 + NAB;                      // NT
    float* edv = es + NT;                       // NT
    float* stg2 = edv + NT;                     // 1024
    float* stc = stg2 + 1024;                   // 2048
    float* psum = stc + 2048;                   // 2*PB*512
    float* psq = psum + 2 * PB * 512;           // 2*PB*512
    float* prm = psq + 2 * PB * 512;            // 8192
    int* flag = (int*)(prm + 8192);             // 16
    int* rp_ab = flag + 16;                     // NAB+1
    int* rp_ag = rp_ab + NAB + 1;               // NAB+1
    int* rp_d = rp_ag + NAB + 1;                // NT+1
    int* gbcnt = rp_d + NT + 1;                 // 3*MAXBUK
    int* gcur = gbcnt + 3 * MAXBUK;             // 3*MAXBUK
    int* bb = gcur + 3 * MAXBUK;                // 3*(MAXBUK+1)
    int* wq = bb + 3 * (MAXBUK + 1);            // 32 work-queue counters
    int* col_ab = wq + 32;                      // EAB
    int* col_ag = col_ab + EAB;                 // EAG
    int* col_d = col_ag + EAG;                  // ED
    u32* stg_ab = (u32*)(col_d + ED);           // EAB
    u32* stg_ag = stg_ab + EAB;                 // EAG
    u32* stg_d = stg_ag + EAG;                  // ED

    u16* wt_gcn = wt4;
    u16* wt_aggcn = wt4 + 65536;
    u16* wt_gat = wt4 + 2 * 65536;
    u16* wt_gat2 = wt4 + 3 * 65536;

    dim3 t256(256), t512(512);
    const int nbg = (NAB + 127) / 128;   // 157 bn partial blocks per graph
    const int nzero = 6 * MAXBUK + 3 * (MAXBUK + 1) + 32;

    detect_k<<<dim3(1), t256, 0, stream>>>((const u16*)x_ab, flag);
    prep_k<<<dim3(1049), t256, 0, stream>>>(
        d_in[2], d_in[6], d_in[10], d_in[14],
        d_in[3], d_in[4], d_in[5], d_in[7], d_in[8], d_in[9],
        d_in[11], d_in[12], d_in[13], d_in[15], d_in[16], d_in[17],
        d_in[22], d_in[23], d_in[24], d_in[18], d_in[19], d_in[20],
        d_in[25], d_in[21], wt4, prm, gbcnt, nzero, flag);

    // bucket-level CSR build (4 dispatches)
    bucket_cnt3_k<<<dim3(157, 3), t256, 0, stream>>>(e_ab, e_ag, e_d, gbcnt);
    bucket_scan3_k<<<dim3(1, 3), t256, 0, stream>>>(gbcnt, bb, rp_ab, rp_ag, rp_d);
    bin3_k<<<dim3(157, 3), t256, 0, stream>>>(e_ab, e_ag, e_d, bb, gcur,
                                              stg_ab, stg_ag, stg_d);
    place3_k<<<dim3(157, 3), t256, 0, stream>>>(stg_ab, stg_ag, stg_d, bb,
                                                rp_ab, rp_ag, rp_d, dv0, dv1,
                                                col_ab, col_ag, col_d);

    // batched GCN stage (5 dispatches)
    gemm2_k<<<dim3((NAB + 63) / 64, 2), t256, 0, stream>>>(x_ab, x_ag, wt_gcn, wt_aggcn,
                                                           flag, bufA, NAB);
    gcn_csr2_k<<<dim3(2048), t256, 0, stream>>>(bufA, rp_ab, rp_ag,
                                                col_ab, col_ag, dv0, dv1,
                                                prm, bufB, NAB, wq);
    bn_stats2_k<<<dim3(nbg, 2), t256, 0, stream>>>(bufB, NAB, psum, psq);
    bn_fin2_k<<<dim3(64, 2), t256, 0, stream>>>(psum, psq, stg2, NAB, nbg);
    bn_apply2_k<<<dim3((NAB * NF / 8 + 255) / 256, 2), t256, 0, stream>>>(bufB, stg2, prm,
                                                                          hcat, NAB);

    // GAT layer 1 (2 dispatches)
    gemm_gat_k<<<dim3((NT + 63) / 64), t256, 0, stream>>>(hcat, wt_gat, bufA, NT,
                                                          prm + P_ASRC, prm + P_ADST,
                                                          es, edv);
    gat_csr_k<<<dim3(2048), t256, 0, stream>>>(bufA, rp_d, col_d, es, edv,
                                               prm + P_BGAT, bufB, NT, 1, wq + 8);
    // GAT layer 2 (2 dispatches)
    gemm_gat_k<<<dim3((NT + 63) / 64), t256, 0, stream>>>(bufB, wt_gat2, bufA, NT,
                                                          prm + P_ASRC2, prm + P_ADST2,
                                                          es, edv);
    gat_csr_k<<<dim3(2048), t256, 0, stream>>>(bufA, rp_d, col_d, es, edv,
                                               prm + P_BGAT2, bufB, NT, 0, wq + 16);

    // batched final stage (3 dispatches)
    bn_stats_cat2_k<<<dim3(nbg, 2), t512, 0, stream>>>(bufB, hcat, NAB, psum, psq);
    bn_fin_cat2_k<<<dim3(128, 2), t256, 0, stream>>>(psum, psq, stc, NAB, nbg);
    final2_k<<<dim3((NAB + 3) / 4, 2), t256, 0, stream>>>(bufB, hcat, stc, prm,
                                                          (float*)d_out, NAB);
}

// Round 7
// 736.896 us; speedup vs baseline: 1.7148x; 1.7148x over previous
//
#include <hip/hip_runtime.h>
#include <hip/hip_bf16.h>
#include <stdint.h>

#define NF 256
#define EPSV 1e-5f
#define PB 160     // max bn partial blocks
#define MAXBUK 160 // max coarse buckets (dst>>8): 157 for NT=40000
// s_getreg imm for HW_REG_XCC_ID (id=20, offset=0, size=4): ((4-1)<<11)|20
#define XCCID_IMM 6164
#define WQS 16     // work-queue counter stride (ints) = one 64B line per slab

typedef unsigned short u16;
typedef unsigned int u32;
typedef short short8 __attribute__((ext_vector_type(8)));
typedef float floatx4 __attribute__((ext_vector_type(4)));

// param block offsets (floats): 12 x 256, then 6 x 512, then 2 x 1
#define P_BGCN 0
#define P_G1 256
#define P_BE1 512
#define P_BAGG 768
#define P_AGG1 1024
#define P_AGBE1 1280
#define P_ASRC 1536
#define P_ADST 1792
#define P_BGAT 2048
#define P_ASRC2 2304
#define P_ADST2 2560
#define P_BGAT2 2816
#define P_G2 3072
#define P_BE2 3584
#define P_WFC 4096
#define P_AGG2 4608
#define P_AGBE2 5120
#define P_WAGFC 5632
#define P_BFC 6144
#define P_BAGFC 6145

__device__ __forceinline__ float bf2f(u16 u) {
    union { unsigned int i; float f; } v; v.i = ((unsigned int)u) << 16; return v.f;
}
__device__ __forceinline__ u16 f2bf(float f) {
    unsigned int x = __float_as_uint(f);
    unsigned int r = x + 0x7fffu + ((x >> 16) & 1u);
    return (u16)(r >> 16);
}
__device__ __forceinline__ float sane(float f) {
    return (f == f && fabsf(f) < 1e30f) ? f : 0.f;
}
__device__ __forceinline__ unsigned int zap2(unsigned int w) {
    if ((w & 0x00007F80u) == 0x00007F80u) w &= 0xFFFF0000u;
    if ((w & 0x7F800000u) == 0x7F800000u) w &= 0x0000FFFFu;
    return w;
}
__device__ __forceinline__ float lrelu(float x) { return x > 0.f ? x : 0.2f * x; }

// 4 bf16 (uint2) -> acc[k] += a * h[k]
__device__ __forceinline__ void fma4u(const uint2 u, float a, float* acc) {
    acc[0] = fmaf(__uint_as_float(u.x << 16), a, acc[0]);
    acc[1] = fmaf(__uint_as_float(u.x & 0xFFFF0000u), a, acc[1]);
    acc[2] = fmaf(__uint_as_float(u.y << 16), a, acc[2]);
    acc[3] = fmaf(__uint_as_float(u.y & 0xFFFF0000u), a, acc[3]);
}
__device__ __forceinline__ void st4hp(u16* p, const float* v) {
    uint2 u;
    u.x = (u32)f2bf(v[0]) | ((u32)f2bf(v[1]) << 16);
    u.y = (u32)f2bf(v[2]) | ((u32)f2bf(v[3]) << 16);
    *(uint2*)p = u;
}
__device__ __forceinline__ void st8h(u16* p, const float* v) {
    uint4 u;
    u.x = (u32)f2bf(v[0]) | ((u32)f2bf(v[1]) << 16);
    u.y = (u32)f2bf(v[2]) | ((u32)f2bf(v[3]) << 16);
    u.z = (u32)f2bf(v[4]) | ((u32)f2bf(v[5]) << 16);
    u.w = (u32)f2bf(v[6]) | ((u32)f2bf(v[7]) << 16);
    *(uint4*)p = u;
}

__device__ __forceinline__ float wredsum(float v) {
#pragma unroll
    for (int o = 32; o > 0; o >>= 1) v += __shfl_xor(v, o, 64);
    return v;
}
__device__ __forceinline__ int wscan_incl(int x, int lane) {
#pragma unroll
    for (int o = 1; o < 64; o <<= 1) {
        int t = __shfl_up(x, o, 64);
        if (lane >= o) x += t;
    }
    return x;
}

// ---------------- dtype detect ----------------
__global__ void detect_k(const u16* __restrict__ x, int* __restrict__ flag) {
    __shared__ int cnt;
    if (threadIdx.x == 0) cnt = 0;
    __syncthreads();
    int c = 0;
#pragma unroll
    for (int k = 0; k < 4; ++k) {
        unsigned int u = x[2 * (threadIdx.x + 256 * k)];
        int e = (int)((u >> 7) & 0xFFu);
        if (u == 0u || (e >= 100 && e <= 140)) c++;
    }
    atomicAdd(&cnt, c);
    __syncthreads();
    if (threadIdx.x == 0) flag[0] = (cnt >= 512) ? 1 : 0;
}

// ---------------- prep: weight fragment-pack + param cvt + counter zero ----------------
__global__ void prep_k(const void* w0, const void* w1, const void* w2, const void* w3,
                       const void* p0, const void* p1, const void* p2, const void* p3,
                       const void* p4, const void* p5, const void* p6, const void* p7,
                       const void* p8, const void* p9, const void* p10, const void* p11,
                       const void* p12, const void* p13, const void* p14, const void* p15,
                       const void* p16, const void* p17, const void* p18, const void* p19,
                       u16* __restrict__ wtf, float* __restrict__ prm,
                       int* __restrict__ zb, int nz,
                       const int* __restrict__ flagp) {
    int f = flagp[0];
    int idx = blockIdx.x * 256 + threadIdx.x;
    if (idx < nz) zb[idx] = 0;
    if (idx < 262144) {
        const void* ws[4] = {w0, w1, w2, w3};
        int wi = idx >> 16;
        int rest = idx & 65535;
        int j = rest & 7;
        int lr = (rest >> 3) & 15;
        int q = (rest >> 7) & 3;
        int nf = (rest >> 9) & 15;
        int ks = (rest >> 13) & 7;
        int n = nf * 16 + lr;
        int k = ks * 32 + q * 8 + j;
        const void* W = ws[wi];
        u16 v;
        if (f) {
            v = ((const u16*)W)[k * NF + n];
            if ((v & 0x7F80u) == 0x7F80u) v = 0;
        } else {
            v = f2bf(sane(((const float*)W)[k * NF + n]));
        }
        wtf[idx] = v;
        return;
    }
    int pidx = idx - 262144;
    if (pidx >= 6146) return;
    const void* ptrs[20] = {p0, p1, p2, p3, p4, p5, p6, p7, p8, p9,
                            p10, p11, p12, p13, p14, p15, p16, p17, p18, p19};
    int t, j;
    if (pidx < 3072) { t = pidx >> 8; j = pidx & 255; }
    else if (pidx < 6144) { t = 12 + ((pidx - 3072) >> 9); j = (pidx - 3072) & 511; }
    else { t = 18 + (pidx - 6144); j = 0; }
    float v = f ? bf2f(((const u16*)ptrs[t])[j]) : ((const float*)ptrs[t])[j];
    prm[pidx] = sane(v);
}

// ---------------- bucket-level CSR build (y = graph: 0=ab, 1=ag, 2=d) ----------------
__global__ __launch_bounds__(256) void bucket_cnt3_k(const int* e0, const int* e1,
                                                     const int* e2,
                                                     int* __restrict__ gbcnt) {
    int y = blockIdx.y;
    const int* ei = (y == 0) ? e0 : (y == 1) ? e1 : e2;
    int E = (y == 2) ? 640000 : 320000;
    int n = (y == 2) ? 40000 : 20000;
    int nbuk = (n + 255) >> 8;
    int base = blockIdx.x * 4096;
    if (base >= E) return;
    __shared__ int l[MAXBUK];
    if (threadIdx.x < nbuk) l[threadIdx.x] = 0;
    __syncthreads();
#pragma unroll
    for (int t = 0; t < 16; ++t) {
        int e = base + t * 256 + threadIdx.x;
        if (e < E) atomicAdd(&l[ei[E + e] >> 8], 1);
    }
    __syncthreads();
    if (threadIdx.x < nbuk) {
        int c = l[threadIdx.x];
        if (c) atomicAdd(&gbcnt[y * MAXBUK + threadIdx.x], c);
    }
}
__global__ __launch_bounds__(256) void bucket_scan3_k(const int* __restrict__ gbcnt,
                                                      int* __restrict__ bb,
                                                      int* rp0, int* rp1, int* rp2) {
    __shared__ int wp[4];
    int y = blockIdx.y;
    int n = (y == 2) ? 40000 : 20000;
    int E = (y == 2) ? 640000 : 320000;
    int nbuk = (n + 255) >> 8;
    int* rp = (y == 0) ? rp0 : (y == 1) ? rp1 : rp2;
    int lane = threadIdx.x & 63, wave = threadIdx.x >> 6;
    int v = (threadIdx.x < nbuk) ? gbcnt[y * MAXBUK + threadIdx.x] : 0;
    int x = wscan_incl(v, lane);
    if (lane == 63) wp[wave] = x;
    __syncthreads();
    int off = 0;
#pragma unroll
    for (int w = 0; w < 4; ++w) off += (w < wave) ? wp[w] : 0;
    if (threadIdx.x < nbuk) bb[y * (MAXBUK + 1) + threadIdx.x] = off + x - v;
    if (threadIdx.x == 0) {
        bb[y * (MAXBUK + 1) + nbuk] = E;
        rp[n] = E;
    }
}
__global__ __launch_bounds__(256) void bin3_k(const int* e0, const int* e1, const int* e2,
                                              const int* __restrict__ bb,
                                              int* __restrict__ gcur,
                                              u32* s0, u32* s1, u32* s2) {
    int y = blockIdx.y;
    const int* ei = (y == 0) ? e0 : (y == 1) ? e1 : e2;
    u32* stg = (y == 0) ? s0 : (y == 1) ? s1 : s2;
    int E = (y == 2) ? 640000 : 320000;
    int n = (y == 2) ? 40000 : 20000;
    int nbuk = (n + 255) >> 8;
    int base = blockIdx.x * 4096;
    if (base >= E) return;
    __shared__ int lcnt[MAXBUK];
    __shared__ int lbase[MAXBUK];
    if (threadIdx.x < nbuk) lcnt[threadIdx.x] = 0;
    __syncthreads();
#pragma unroll
    for (int t = 0; t < 16; ++t) {
        int e = base + t * 256 + threadIdx.x;
        if (e < E) atomicAdd(&lcnt[ei[E + e] >> 8], 1);
    }
    __syncthreads();
    if (threadIdx.x < nbuk) {
        int cnt = lcnt[threadIdx.x];
        int g = cnt ? atomicAdd(&gcur[y * MAXBUK + threadIdx.x], cnt) : 0;
        lbase[threadIdx.x] = bb[y * (MAXBUK + 1) + threadIdx.x] + g;
        lcnt[threadIdx.x] = 0;
    }
    __syncthreads();
#pragma unroll
    for (int t = 0; t < 16; ++t) {
        int e = base + t * 256 + threadIdx.x;
        if (e < E) {
            int s = ei[e], d = ei[E + e];
            int b = d >> 8;
            int r = atomicAdd(&lcnt[b], 1);
            stg[lbase[b] + r] = (u32)s | ((u32)(d & 255) << 16);
        }
    }
}
__global__ __launch_bounds__(256) void place3_k(const u32* s0, const u32* s1, const u32* s2,
                                                const int* __restrict__ bb,
                                                int* rp0, int* rp1, int* rp2,
                                                float* dv0, float* dv1,
                                                int* c0, int* c1, int* c2) {
    __shared__ int wp[4];
    __shared__ int lcnt[256];
    __shared__ int lrp[256];
    int y = blockIdx.y;
    int b = blockIdx.x;
    int n = (y == 2) ? 40000 : 20000;
    int nbuk = (n + 255) >> 8;
    if (b >= nbuk) return;
    const u32* stg = (y == 0) ? s0 : (y == 1) ? s1 : s2;
    int* rp = (y == 0) ? rp0 : (y == 1) ? rp1 : rp2;
    int* col = (y == 0) ? c0 : (y == 1) ? c1 : c2;
    int d0 = b << 8;
    int dn = min(256, n - d0);
    int base = bb[y * (MAXBUK + 1) + b];
    int endv = bb[y * (MAXBUK + 1) + b + 1];
    lcnt[threadIdx.x] = 0;
    __syncthreads();
    for (int j = base + threadIdx.x; j < endv; j += 256)
        atomicAdd(&lcnt[stg[j] >> 16], 1);
    __syncthreads();
    int lane = threadIdx.x & 63, wave = threadIdx.x >> 6;
    int v = lcnt[threadIdx.x];
    int x = wscan_incl(v, lane);
    if (lane == 63) wp[wave] = x;
    __syncthreads();
    int off = 0;
#pragma unroll
    for (int w = 0; w < 4; ++w) off += (w < wave) ? wp[w] : 0;
    int excl = base + off + x - v;
    lrp[threadIdx.x] = excl;
    if (threadIdx.x < dn) {
        rp[d0 + threadIdx.x] = excl;
        if (y == 0) dv0[d0 + threadIdx.x] = rsqrtf((float)(v + 1));
        else if (y == 1) dv1[d0 + threadIdx.x] = rsqrtf((float)(v + 1));
    }
    lcnt[threadIdx.x] = 0;
    __syncthreads();
    for (int j = base + threadIdx.x; j < endv; j += 256) {
        u32 rec = stg[j];
        int dl = (int)(rec >> 16);
        int s = (int)(rec & 0xFFFFu);
        int r = atomicAdd(&lcnt[dl], 1);
        col[lrp[dl] + r] = s;
    }
}

// ---------------- batched GCN GEMM (y = graph), slab-major C output ----------
// C layout: 8 slabs of [M][32] bf16 per graph (slab = channel>>5).
__global__ __launch_bounds__(256) void gemm2_k(const void* A0, const void* A1,
                                               const u16* __restrict__ Wtf0,
                                               const u16* __restrict__ Wtf1,
                                               const int* __restrict__ flagp,
                                               u16* __restrict__ C, int M) {
    int f = flagp[0];
    int y = blockIdx.y;
    const void* Aptr = y ? A1 : A0;
    const u16* Wtf = y ? Wtf1 : Wtf0;
    u16* Cp = C + (size_t)y * M * NF;
    int wave = threadIdx.x >> 6, lane = threadIdx.x & 63;
    int lr = lane & 15, q = lane >> 4;
    int arow = blockIdx.x * 64 + wave * 16 + lr;
    bool rok = arow < M;
    floatx4 acc[16];
#pragma unroll
    for (int nf = 0; nf < 16; ++nf) acc[nf] = (floatx4){0.f, 0.f, 0.f, 0.f};
    const u16* a16 = (const u16*)Aptr + (size_t)arow * NF;
    const float* a32 = (const float*)Aptr + (size_t)arow * NF;
#pragma unroll
    for (int ks = 0; ks < 8; ++ks) {
        int kk = ks * 32 + q * 8;
        union { u16 s[8]; uint4 u; short8 v; } a;
        if (!rok) {
            a.u = make_uint4(0u, 0u, 0u, 0u);
        } else if (f) {
            a.u = *(const uint4*)(a16 + kk);
            a.u.x = zap2(a.u.x); a.u.y = zap2(a.u.y);
            a.u.z = zap2(a.u.z); a.u.w = zap2(a.u.w);
        } else {
            float4 f0 = *(const float4*)(a32 + kk);
            float4 f1 = *(const float4*)(a32 + kk + 4);
            a.s[0] = f2bf(sane(f0.x)); a.s[1] = f2bf(sane(f0.y));
            a.s[2] = f2bf(sane(f0.z)); a.s[3] = f2bf(sane(f0.w));
            a.s[4] = f2bf(sane(f1.x)); a.s[5] = f2bf(sane(f1.y));
            a.s[6] = f2bf(sane(f1.z)); a.s[7] = f2bf(sane(f1.w));
        }
        const u16* bbase = Wtf + ks * 8192 + lane * 8;
#pragma unroll
        for (int nf = 0; nf < 16; ++nf) {
            short8 b = *(const short8*)(bbase + nf * 512);
            acc[nf] = __builtin_amdgcn_mfma_f32_16x16x32_bf16(a.v, b, acc[nf], 0, 0, 0);
        }
    }
#pragma unroll
    for (int nf = 0; nf < 16; ++nf) {
        int colb = nf * 16 + lr;
        u16* dst = Cp + (size_t)(colb >> 5) * M * 32 + (colb & 31);
#pragma unroll
        for (int rr = 0; rr < 4; ++rr) {
            int gr = blockIdx.x * 64 + wave * 16 + q * 4 + rr;
            if (gr < M) dst[(size_t)gr * 32] = f2bf(acc[nf][rr]);
        }
    }
}

// ---------------- GAT GEMM MR=1, slab-major C, fused scores epilogue ----------------
__global__ __launch_bounds__(256) void gemm_gat_k(const u16* __restrict__ Aptr,
                                                  const u16* __restrict__ Wtf,
                                                  u16* __restrict__ C, int M,
                                                  const float* __restrict__ as_,
                                                  const float* __restrict__ ad_,
                                                  float* __restrict__ es,
                                                  float* __restrict__ ed) {
    int wave = threadIdx.x >> 6, lane = threadIdx.x & 63;
    int lr = lane & 15, q = lane >> 4;
    int arow = blockIdx.x * 64 + wave * 16 + lr;
    bool rok = arow < M;
    floatx4 acc[16];
#pragma unroll
    for (int nf = 0; nf < 16; ++nf) acc[nf] = (floatx4){0.f, 0.f, 0.f, 0.f};
    const u16* a16 = Aptr + (size_t)arow * NF;
#pragma unroll
    for (int ks = 0; ks < 8; ++ks) {
        int kk = ks * 32 + q * 8;
        union { uint4 u; short8 v; } a;
        a.u = rok ? *(const uint4*)(a16 + kk) : make_uint4(0u, 0u, 0u, 0u);
        const u16* bbase = Wtf + ks * 8192 + lane * 8;
#pragma unroll
        for (int nf = 0; nf < 16; ++nf) {
            short8 b = *(const short8*)(bbase + nf * 512);
            acc[nf] = __builtin_amdgcn_mfma_f32_16x16x32_bf16(a.v, b, acc[nf], 0, 0, 0);
        }
    }
#pragma unroll
    for (int nf = 0; nf < 16; ++nf) {
        int colb = nf * 16 + lr;
        u16* dst = C + (size_t)(colb >> 5) * M * 32 + (colb & 31);
#pragma unroll
        for (int rr = 0; rr < 4; ++rr) {
            int gr = blockIdx.x * 64 + wave * 16 + q * 4 + rr;
            if (gr < M) dst[(size_t)gr * 32] = f2bf(acc[nf][rr]);
        }
    }
    float asl[16], adl[16];
#pragma unroll
    for (int nf = 0; nf < 16; ++nf) { asl[nf] = as_[nf * 16 + lr]; adl[nf] = ad_[nf * 16 + lr]; }
#pragma unroll
    for (int rr = 0; rr < 4; ++rr) {
        float s1 = 0.f, s2 = 0.f;
#pragma unroll
        for (int nf = 0; nf < 16; ++nf) {
            s1 += acc[nf][rr] * asl[nf];
            s2 += acc[nf][rr] * adl[nf];
        }
#pragma unroll
        for (int o = 1; o < 16; o <<= 1) {
            s1 += __shfl_xor(s1, o, 64);
            s2 += __shfl_xor(s2, o, 64);
        }
        int gr = blockIdx.x * 64 + wave * 16 + q * 4 + rr;
        if (lr == 0 && gr < M) { es[gr] = s1; ed[gr] = s2; }
    }
}

// ---------------- XCC-pinned GCN aggregation, group-per-dst (slab-major h) ----------
// 8-lane group owns one dst: lane covers 4 ch of the 32-ch slab; col/dinv loads
// are group-uniform (HW broadcast); NO cross-lane reduction. Ticket = 2048 dsts.
__global__ __launch_bounds__(256) void gcn_csr2_k(const u16* __restrict__ h,
                                                  const int* rp0, const int* rp1,
                                                  const int* c0, const int* c1,
                                                  const float* dv0, const float* dv1,
                                                  const float* __restrict__ prm,
                                                  u16* __restrict__ out, int n,
                                                  int* __restrict__ wq) {
    __shared__ int ls;
    int li = threadIdx.x & 7, grp = threadIdx.x >> 3;
    int cl = li * 4;
    int xcd = __builtin_amdgcn_s_getreg(XCCID_IMM) & 7;
    const int TPG = 79;        // tickets per graph: ceil(20000/256)
    const int LIM = 2 * TPG;   // 158 per slab queue
    for (int d = 0; d < 8; ++d) {
        int slab = (xcd + d) & 7;
        // monotonic drained pre-check (block-uniform via LDS broadcast)
        if (threadIdx.x == 0) ls = *(volatile int*)&wq[slab * WQS];
        __syncthreads();
        int pre = ls;
        __syncthreads();
        if (pre >= LIM) continue;
        for (int it = 0; it < 4096; ++it) {   // bounded (defensive)
            if (threadIdx.x == 0) ls = atomicAdd(&wq[slab * WQS], 1);
            __syncthreads();
            int t = ls;
            __syncthreads();
            if (t >= LIM) break;
            int y = t >= TPG;
            int base = (t - y * TPG) * 256 + grp * 8;
            const int* rp = y ? rp1 : rp0;
            const int* col = y ? c1 : c0;
            const float* dinv = y ? dv1 : dv0;
            const float* b = prm + (y ? P_BAGG : P_BGCN) + slab * 32;
            const u16* hs = h + (size_t)y * n * NF + (size_t)slab * n * 32;
            u16* ob = out + (size_t)y * n * NF;
            float b0 = b[cl], b1 = b[cl + 1], b2 = b[cl + 2], b3 = b[cl + 3];
            for (int k = 0; k < 8; ++k) {
                int i = base + k;
                if (i >= n) break;
                int beg = rp[i], end = rp[i + 1];
                float di = dinv[i];
                uint2 us = *(const uint2*)(hs + (size_t)i * 32 + cl);
                float acc[4] = {0.f, 0.f, 0.f, 0.f};
                fma4u(us, di * di, acc);
                int j = beg;
                for (; j + 1 < end; j += 2) {
                    int s0 = col[j], s1 = col[j + 1];
                    float n0 = dinv[s0] * di, n1 = dinv[s1] * di;
                    uint2 u0 = *(const uint2*)(hs + (size_t)s0 * 32 + cl);
                    uint2 u1 = *(const uint2*)(hs + (size_t)s1 * 32 + cl);
                    fma4u(u0, n0, acc);
                    fma4u(u1, n1, acc);
                }
                if (j < end) {
                    int s = col[j];
                    uint2 u = *(const uint2*)(hs + (size_t)s * 32 + cl);
                    fma4u(u, dinv[s] * di, acc);
                }
                float r[4];
                r[0] = acc[0] + b0; r[1] = acc[1] + b1;
                r[2] = acc[2] + b2; r[3] = acc[3] + b3;
                st4hp(ob + (size_t)i * NF + slab * 32 + cl, r);
            }
        }
    }
}

// ---------------- BN partial stats (no atomics) ----------------
__global__ void bn_stats2_k(const u16* __restrict__ x, int n,
                            float* __restrict__ psum, float* __restrict__ psq) {
    int y = blockIdx.y;
    int c = threadIdx.x;  // 256
    int r0 = blockIdx.x * 128;
    int rend = min(r0 + 128, n);
    const u16* xb = x + (size_t)y * n * NF;
    float s = 0.f, qq = 0.f;
    for (int r = r0; r < rend; ++r) {
        float v = bf2f(xb[(size_t)r * NF + c]);
        s += v; qq += v * v;
    }
    size_t o = (size_t)(y * PB + blockIdx.x) * 512 + c;
    psum[o] = s; psq[o] = qq;
}
// wave-per-channel finalize
__global__ void bn_fin2_k(const float* __restrict__ psum, const float* __restrict__ psq,
                          float* __restrict__ stg, int n, int nb) {
    int y = blockIdx.y;
    int wave = threadIdx.x >> 6, lane = threadIdx.x & 63;
    int c = blockIdx.x * 4 + wave;   // 256 channels, grid.x = 64
    float s = 0.f, qq = 0.f;
    for (int b = lane; b < nb; b += 64) {
        size_t o = (size_t)(y * PB + b) * 512 + c;
        s += psum[o]; qq += psq[o];
    }
    s = wredsum(s);
    qq = wredsum(qq);
    if (lane == 0) {
        float inv_n = 1.0f / (float)n;
        float mean = s * inv_n;
        float var = fmaxf(qq * inv_n - mean * mean, 0.f);
        stg[y * 512 + c] = mean;
        stg[y * 512 + 256 + c] = rsqrtf(var + EPSV);
    }
}
// vectorized: 8 values per thread (uint4 in / uint4 out)
__global__ void bn_apply2_k(const u16* __restrict__ x, const float* __restrict__ stg,
                            const float* __restrict__ prm, u16* __restrict__ out, int n) {
    int y = blockIdx.y;
    int t = blockIdx.x * 256 + threadIdx.x;
    if (t >= n * (NF / 8)) return;
    int c = (t & 31) * 8;
    const float* st = stg + y * 512;
    const float* g = prm + (y ? P_AGG1 : P_G1);
    const float* be = prm + (y ? P_AGBE1 : P_BE1);
    uint4 u = *(const uint4*)(x + (size_t)y * n * NF + (size_t)t * 8);
    float v[8];
    v[0] = __uint_as_float(u.x << 16); v[1] = __uint_as_float(u.x & 0xFFFF0000u);
    v[2] = __uint_as_float(u.y << 16); v[3] = __uint_as_float(u.y & 0xFFFF0000u);
    v[4] = __uint_as_float(u.z << 16); v[5] = __uint_as_float(u.z & 0xFFFF0000u);
    v[6] = __uint_as_float(u.w << 16); v[7] = __uint_as_float(u.w & 0xFFFF0000u);
    float r[8];
#pragma unroll
    for (int k = 0; k < 8; ++k) {
        int cc = c + k;
        float w = (v[k] - st[cc]) * st[256 + cc] * g[cc] + be[cc];
        r[k] = fmaxf(w, 0.f);
    }
    st8h(out + (size_t)y * n * NF + (size_t)t * 8, r);
}

// ---------------- XCC-pinned fused GAT aggregation, group-per-dst ----------------
__global__ __launch_bounds__(256) void gat_csr_k(const u16* __restrict__ h,
                                                 const int* __restrict__ rp,
                                                 const int* __restrict__ col,
                                                 const float* __restrict__ es,
                                                 const float* __restrict__ ed,
                                                 const float* __restrict__ b,
                                                 u16* __restrict__ out, int n,
                                                 int do_relu, int* __restrict__ wq) {
    __shared__ int ls;
    int li = threadIdx.x & 7, grp = threadIdx.x >> 3;
    int cl = li * 4;
    int xcd = __builtin_amdgcn_s_getreg(XCCID_IMM) & 7;
    const int LIM = 157;   // ceil(40000/256) tickets per slab queue
    for (int d = 0; d < 8; ++d) {
        int slab = (xcd + d) & 7;
        const u16* hs = h + (size_t)slab * n * 32;
        const float* bs = b + slab * 32;
        if (threadIdx.x == 0) ls = *(volatile int*)&wq[slab * WQS];
        __syncthreads();
        int pre = ls;
        __syncthreads();
        if (pre >= LIM) continue;
        for (int it = 0; it < 4096; ++it) {   // bounded (defensive)
            if (threadIdx.x == 0) ls = atomicAdd(&wq[slab * WQS], 1);
            __syncthreads();
            int t = ls;
            __syncthreads();
            if (t >= LIM) break;
            int base = t * 256 + grp * 8;
            float bv0 = bs[cl], bv1 = bs[cl + 1], bv2 = bs[cl + 2], bv3 = bs[cl + 3];
            for (int k = 0; k < 8; ++k) {
                int i = base + k;
                if (i >= n) break;
                int beg = rp[i], end = rp[i + 1];
                float edi = ed[i];
                float ws = __expf(lrelu(es[i] + edi));
                float ssum = ws;
                uint2 us = *(const uint2*)(hs + (size_t)i * 32 + cl);
                float acc[4] = {0.f, 0.f, 0.f, 0.f};
                fma4u(us, ws, acc);
                int j = beg;
                for (; j + 1 < end; j += 2) {
                    int s0 = col[j], s1 = col[j + 1];
                    float a0 = __expf(lrelu(es[s0] + edi));
                    float a1 = __expf(lrelu(es[s1] + edi));
                    uint2 u0 = *(const uint2*)(hs + (size_t)s0 * 32 + cl);
                    uint2 u1 = *(const uint2*)(hs + (size_t)s1 * 32 + cl);
                    ssum += a0 + a1;
                    fma4u(u0, a0, acc);
                    fma4u(u1, a1, acc);
                }
                if (j < end) {
                    int s = col[j];
                    float a = __expf(lrelu(es[s] + edi));
                    uint2 u = *(const uint2*)(hs + (size_t)s * 32 + cl);
                    ssum += a;
                    fma4u(u, a, acc);
                }
                float inv = 1.0f / ssum;
                float r[4];
                r[0] = bv0 + acc[0] * inv; r[1] = bv1 + acc[1] * inv;
                r[2] = bv2 + acc[2] * inv; r[3] = bv3 + acc[3] * inv;
                if (do_relu) {
                    r[0] = fmaxf(r[0], 0.f); r[1] = fmaxf(r[1], 0.f);
                    r[2] = fmaxf(r[2], 0.f); r[3] = fmaxf(r[3], 0.f);
                }
                st4hp(out + (size_t)i * NF + slab * 32 + cl, r);
            }
        }
    }
}

// ---------------- batched final-stage BN stats over cat(x,h) (512 ch) ----------------
__global__ void bn_stats_cat2_k(const u16* __restrict__ xp, const u16* __restrict__ hp,
                                int n, float* __restrict__ psum, float* __restrict__ psq) {
    int y = blockIdx.y;
    int c = threadIdx.x;  // 512
    int r0 = blockIdx.x * 128;
    int rend = min(r0 + 128, n);
    const u16* src = ((c < 256) ? xp : hp) + (size_t)y * n * NF;
    int cc = c & 255;
    float s = 0.f, qq = 0.f;
    for (int r = r0; r < rend; ++r) {
        float v = bf2f(src[(size_t)r * NF + cc]);
        s += v; qq += v * v;
    }
    size_t o = (size_t)(y * PB + blockIdx.x) * 512 + c;
    psum[o] = s; psq[o] = qq;
}
// wave-per-channel finalize (512 channels)
__global__ void bn_fin_cat2_k(const float* __restrict__ psum, const float* __restrict__ psq,
                              float* __restrict__ stc, int n, int nb) {
    int y = blockIdx.y;
    int wave = threadIdx.x >> 6, lane = threadIdx.x & 63;
    int c = blockIdx.x * 4 + wave;   // 512 channels, grid.x = 128
    float s = 0.f, qq = 0.f;
    for (int b = lane; b < nb; b += 64) {
        size_t o = (size_t)(y * PB + b) * 512 + c;
        s += psum[o]; qq += psq[o];
    }
    s = wredsum(s);
    qq = wredsum(qq);
    if (lane == 0) {
        float inv_n = 1.0f / (float)n;
        float mean = s * inv_n;
        float var = fmaxf(qq * inv_n - mean * mean, 0.f);
        stc[y * 1024 + c] = mean;
        stc[y * 1024 + 512 + c] = rsqrtf(var + EPSV);
    }
}
__global__ void final2_k(const u16* __restrict__ xp, const u16* __restrict__ hp,
                         const float* __restrict__ stc, const float* __restrict__ prm,
                         float* __restrict__ out, int n) {
    int y = blockIdx.y;
    int wave = threadIdx.x >> 6, lane = threadIdx.x & 63;
    int i = blockIdx.x * 4 + wave;
    if (i >= n) return;
    const float* st = stc + y * 1024;
    const float* g = prm + (y ? P_AGG2 : P_G2);
    const float* be = prm + (y ? P_AGBE2 : P_BE2);
    const float* w = prm + (y ? P_WAGFC : P_WFC);
    float bias = prm[y ? P_BAGFC : P_BFC];
    const u16* src = (((lane < 32) ? xp : hp) + (size_t)y * n * NF) + (size_t)i * NF
                     + (lane < 32 ? lane * 8 : (lane - 32) * 8);
    uint4 u = *(const uint4*)src;
    float vv[8];
    vv[0] = bf2f((u16)(u.x & 0xFFFFu)); vv[1] = bf2f((u16)(u.x >> 16));
    vv[2] = bf2f((u16)(u.y & 0xFFFFu)); vv[3] = bf2f((u16)(u.y >> 16));
    vv[4] = bf2f((u16)(u.z & 0xFFFFu)); vv[5] = bf2f((u16)(u.z >> 16));
    vv[6] = bf2f((u16)(u.w & 0xFFFFu)); vv[7] = bf2f((u16)(u.w >> 16));
    int c0 = lane * 8;
    float acc = 0.f;
#pragma unroll
    for (int j = 0; j < 8; ++j) {
        int c = c0 + j;
        float v = (vv[j] - st[c]) * st[512 + c] * g[c] + be[c];
        v = fmaxf(v, 0.f);
        acc += v * w[c];
    }
    acc = wredsum(acc);
    if (lane == 0) out[(size_t)y * 20000 + i] = acc + bias;
}

// ---------------- host ----------------
extern "C" void kernel_launch(void* const* d_in, const int* in_sizes, int n_in,
                              void* d_out, int out_size, void* d_ws, size_t ws_size,
                              hipStream_t stream) {
    const void* x_ab = d_in[0];
    const void* x_ag = d_in[1];
    const int* e_ab = (const int*)d_in[26];
    const int* e_ag = (const int*)d_in[27];
    const int* e_d = (const int*)d_in[28];

    const int NAB = 20000, NT = 40000;
    const int EAB = 320000, EAG = 320000, ED = 640000;

    u16* hcat = (u16*)d_ws;                     // NT*NF u16
    u16* bufA = hcat + (size_t)NT * NF;         // NT*NF u16
    u16* bufB = bufA + (size_t)NT * NF;         // NT*NF u16
    u16* wt4 = bufB + (size_t)NT * NF;          // 4*65536 u16
    float* dv0 = (float*)(wt4 + 4 * 65536);     // NAB
    float* dv1 = dv0 + NAB;                     // NAB
    float* es = dv1 + NAB;                      // NT
    float* edv = es + NT;                       // NT
    float* stg2 = edv + NT;                     // 1024
    float* stc = stg2 + 1024;                   // 2048
    float* psum = stc + 2048;                   // 2*PB*512
    float* psq = psum + 2 * PB * 512;           // 2*PB*512
    float* prm = psq + 2 * PB * 512;            // 8192
    int* flag = (int*)(prm + 8192);             // 16
    int* rp_ab = flag + 16;                     // NAB+1
    int* rp_ag = rp_ab + NAB + 1;               // NAB+1
    int* rp_d = rp_ag + NAB + 1;                // NT+1
    int* gbcnt = rp_d + NT + 1;                 // 3*MAXBUK
    int* gcur = gbcnt + 3 * MAXBUK;             // 3*MAXBUK
    int* bb = gcur + 3 * MAXBUK;                // 3*(MAXBUK+1)
    int* wq = bb + 3 * (MAXBUK + 1);            // 3*8*WQS work-queue counters
    int* col_ab = wq + 24 * WQS;                // EAB
    int* col_ag = col_ab + EAB;                 // EAG
    int* col_d = col_ag + EAG;                  // ED
    u32* stg_ab = (u32*)(col_d + ED);           // EAB
    u32* stg_ag = stg_ab + EAB;                 // EAG
    u32* stg_d = stg_ag + EAG;                  // ED

    u16* wt_gcn = wt4;
    u16* wt_aggcn = wt4 + 65536;
    u16* wt_gat = wt4 + 2 * 65536;
    u16* wt_gat2 = wt4 + 3 * 65536;

    dim3 t256(256), t512(512);
    const int nbg = (NAB + 127) / 128;   // 157 bn partial blocks per graph
    const int nzero = 6 * MAXBUK + 3 * (MAXBUK + 1) + 24 * WQS;

    detect_k<<<dim3(1), t256, 0, stream>>>((const u16*)x_ab, flag);
    prep_k<<<dim3(1049), t256, 0, stream>>>(
        d_in[2], d_in[6], d_in[10], d_in[14],
        d_in[3], d_in[4], d_in[5], d_in[7], d_in[8], d_in[9],
        d_in[11], d_in[12], d_in[13], d_in[15], d_in[16], d_in[17],
        d_in[22], d_in[23], d_in[24], d_in[18], d_in[19], d_in[20],
        d_in[25], d_in[21], wt4, prm, gbcnt, nzero, flag);

    // bucket-level CSR build (4 dispatches)
    bucket_cnt3_k<<<dim3(157, 3), t256, 0, stream>>>(e_ab, e_ag, e_d, gbcnt);
    bucket_scan3_k<<<dim3(1, 3), t256, 0, stream>>>(gbcnt, bb, rp_ab, rp_ag, rp_d);
    bin3_k<<<dim3(157, 3), t256, 0, stream>>>(e_ab, e_ag, e_d, bb, gcur,
                                              stg_ab, stg_ag, stg_d);
    place3_k<<<dim3(157, 3), t256, 0, stream>>>(stg_ab, stg_ag, stg_d, bb,
                                                rp_ab, rp_ag, rp_d, dv0, dv1,
                                                col_ab, col_ag, col_d);

    // batched GCN stage (5 dispatches)
    gemm2_k<<<dim3((NAB + 63) / 64, 2), t256, 0, stream>>>(x_ab, x_ag, wt_gcn, wt_aggcn,
                                                           flag, bufA, NAB);
    gcn_csr2_k<<<dim3(2048), t256, 0, stream>>>(bufA, rp_ab, rp_ag,
                                                col_ab, col_ag, dv0, dv1,
                                                prm, bufB, NAB, wq);
    bn_stats2_k<<<dim3(nbg, 2), t256, 0, stream>>>(bufB, NAB, psum, psq);
    bn_fin2_k<<<dim3(64, 2), t256, 0, stream>>>(psum, psq, stg2, NAB, nbg);
    bn_apply2_k<<<dim3((NAB * NF / 8 + 255) / 256, 2), t256, 0, stream>>>(bufB, stg2, prm,
                                                                          hcat, NAB);

    // GAT layer 1 (2 dispatches)
    gemm_gat_k<<<dim3((NT + 63) / 64), t256, 0, stream>>>(hcat, wt_gat, bufA, NT,
                                                          prm + P_ASRC, prm + P_ADST,
                                                          es, edv);
    gat_csr_k<<<dim3(2048), t256, 0, stream>>>(bufA, rp_d, col_d, es, edv,
                                               prm + P_BGAT, bufB, NT, 1, wq + 8 * WQS);
    // GAT layer 2 (2 dispatches)
    gemm_gat_k<<<dim3((NT + 63) / 64), t256, 0, stream>>>(bufB, wt_gat2, bufA, NT,
                                                          prm + P_ASRC2, prm + P_ADST2,
                                                          es, edv);
    gat_csr_k<<<dim3(2048), t256, 0, stream>>>(bufA, rp_d, col_d, es, edv,
                                               prm + P_BGAT2, bufB, NT, 0, wq + 16 * WQS);

    // batched final stage (3 dispatches)
    bn_stats_cat2_k<<<dim3(nbg, 2), t512, 0, stream>>>(bufB, hcat, NAB, psum, psq);
    bn_fin_cat2_k<<<dim3(128, 2), t256, 0, stream>>>(psum, psq, stc, NAB, nbg);
    final2_k<<<dim3((NAB + 3) / 4, 2), t256, 0, stream>>>(bufB, hcat, stc, prm,
                                                          (float*)d_out, NAB);
}

// Round 8
// 645.265 us; speedup vs baseline: 1.9583x; 1.1420x over previous
//
#include <hip/hip_runtime.h>
#include <hip/hip_bf16.h>
#include <stdint.h>

#define NF 256
#define EPSV 1e-5f
#define PB 160     // max bn partial blocks

typedef unsigned short u16;
typedef unsigned int u32;
typedef short short8 __attribute__((ext_vector_type(8)));
typedef float floatx4 __attribute__((ext_vector_type(4)));

// param block offsets (floats): 12 x 256, then 6 x 512, then 2 x 1
#define P_BGCN 0
#define P_G1 256
#define P_BE1 512
#define P_BAGG 768
#define P_AGG1 1024
#define P_AGBE1 1280
#define P_ASRC 1536
#define P_ADST 1792
#define P_BGAT 2048
#define P_ASRC2 2304
#define P_ADST2 2560
#define P_BGAT2 2816
#define P_G2 3072
#define P_BE2 3584
#define P_WFC 4096
#define P_AGG2 4608
#define P_AGBE2 5120
#define P_WAGFC 5632
#define P_BFC 6144
#define P_BAGFC 6145

__device__ __forceinline__ float bf2f(u16 u) {
    union { unsigned int i; float f; } v; v.i = ((unsigned int)u) << 16; return v.f;
}
__device__ __forceinline__ u16 f2bf(float f) {
    unsigned int x = __float_as_uint(f);
    unsigned int r = x + 0x7fffu + ((x >> 16) & 1u);
    return (u16)(r >> 16);
}
__device__ __forceinline__ float sane(float f) {
    return (f == f && fabsf(f) < 1e30f) ? f : 0.f;
}
__device__ __forceinline__ unsigned int zap2(unsigned int w) {
    if ((w & 0x00007F80u) == 0x00007F80u) w &= 0xFFFF0000u;
    if ((w & 0x7F800000u) == 0x7F800000u) w &= 0x0000FFFFu;
    return w;
}
__device__ __forceinline__ float lrelu(float x) { return x > 0.f ? x : 0.2f * x; }

// 8 bf16 (uint4) -> acc[k] += a * h[k]
__device__ __forceinline__ void fma8(const uint4 u, float a, float* acc) {
    acc[0] = fmaf(__uint_as_float(u.x << 16), a, acc[0]);
    acc[1] = fmaf(__uint_as_float(u.x & 0xFFFF0000u), a, acc[1]);
    acc[2] = fmaf(__uint_as_float(u.y << 16), a, acc[2]);
    acc[3] = fmaf(__uint_as_float(u.y & 0xFFFF0000u), a, acc[3]);
    acc[4] = fmaf(__uint_as_float(u.z << 16), a, acc[4]);
    acc[5] = fmaf(__uint_as_float(u.z & 0xFFFF0000u), a, acc[5]);
    acc[6] = fmaf(__uint_as_float(u.w << 16), a, acc[6]);
    acc[7] = fmaf(__uint_as_float(u.w & 0xFFFF0000u), a, acc[7]);
}
__device__ __forceinline__ void st8h(u16* p, const float* v) {
    uint4 u;
    u.x = (u32)f2bf(v[0]) | ((u32)f2bf(v[1]) << 16);
    u.y = (u32)f2bf(v[2]) | ((u32)f2bf(v[3]) << 16);
    u.z = (u32)f2bf(v[4]) | ((u32)f2bf(v[5]) << 16);
    u.w = (u32)f2bf(v[6]) | ((u32)f2bf(v[7]) << 16);
    *(uint4*)p = u;
}

__device__ __forceinline__ float wredsum(float v) {
#pragma unroll
    for (int o = 32; o > 0; o >>= 1) v += __shfl_xor(v, o, 64);
    return v;
}
__device__ __forceinline__ int wscan_incl(int x, int lane) {
#pragma unroll
    for (int o = 1; o < 64; o <<= 1) {
        int t = __shfl_up(x, o, 64);
        if (lane >= o) x += t;
    }
    return x;
}

// ---------------- dtype detect ----------------
__global__ void detect_k(const u16* __restrict__ x, int* __restrict__ flag) {
    __shared__ int cnt;
    if (threadIdx.x == 0) cnt = 0;
    __syncthreads();
    int c = 0;
#pragma unroll
    for (int k = 0; k < 4; ++k) {
        unsigned int u = x[2 * (threadIdx.x + 256 * k)];
        int e = (int)((u >> 7) & 0xFFu);
        if (u == 0u || (e >= 100 && e <= 140)) c++;
    }
    atomicAdd(&cnt, c);
    __syncthreads();
    if (threadIdx.x == 0) flag[0] = (cnt >= 512) ? 1 : 0;
}

// ---------------- prep: weight fragment-pack + param cvt + counter zero ----------------
__global__ void prep_k(const void* w0, const void* w1, const void* w2, const void* w3,
                       const void* p0, const void* p1, const void* p2, const void* p3,
                       const void* p4, const void* p5, const void* p6, const void* p7,
                       const void* p8, const void* p9, const void* p10, const void* p11,
                       const void* p12, const void* p13, const void* p14, const void* p15,
                       const void* p16, const void* p17, const void* p18, const void* p19,
                       u16* __restrict__ wtf, float* __restrict__ prm,
                       int* __restrict__ zb, int nz,
                       const int* __restrict__ flagp) {
    int f = flagp[0];
    int idx = blockIdx.x * 256 + threadIdx.x;
    if (idx < nz) zb[idx] = 0;
    if (idx < 262144) {
        const void* ws[4] = {w0, w1, w2, w3};
        int wi = idx >> 16;
        int rest = idx & 65535;
        int j = rest & 7;
        int lr = (rest >> 3) & 15;
        int q = (rest >> 7) & 3;
        int nf = (rest >> 9) & 15;
        int ks = (rest >> 13) & 7;
        int n = nf * 16 + lr;
        int k = ks * 32 + q * 8 + j;
        const void* W = ws[wi];
        u16 v;
        if (f) {
            v = ((const u16*)W)[k * NF + n];
            if ((v & 0x7F80u) == 0x7F80u) v = 0;
        } else {
            v = f2bf(sane(((const float*)W)[k * NF + n]));
        }
        wtf[idx] = v;
        return;
    }
    int pidx = idx - 262144;
    if (pidx >= 6146) return;
    const void* ptrs[20] = {p0, p1, p2, p3, p4, p5, p6, p7, p8, p9,
                            p10, p11, p12, p13, p14, p15, p16, p17, p18, p19};
    int t, j;
    if (pidx < 3072) { t = pidx >> 8; j = pidx & 255; }
    else if (pidx < 6144) { t = 12 + ((pidx - 3072) >> 9); j = (pidx - 3072) & 511; }
    else { t = 18 + (pidx - 6144); j = 0; }
    float v = f ? bf2f(((const u16*)ptrs[t])[j]) : ((const float*)ptrs[t])[j];
    prm[pidx] = sane(v);
}

// ---------------- CSR build v2: global-atomic count -> scan -> place ----------------
// pass 1: per-dst degree counts via global atomics (deg arrays L2-resident, 160KB)
__global__ __launch_bounds__(256) void cnt3_k(const int* e0, const int* e1, const int* e2,
                                              int* rp0, int* rp1, int* rp2) {
    int y = blockIdx.y;
    const int* ei = (y == 0) ? e0 : (y == 1) ? e1 : e2;
    int E = (y == 2) ? 640000 : 320000;
    int* rp = (y == 0) ? rp0 : (y == 1) ? rp1 : rp2;
    int base = blockIdx.x * 4096;
    if (base >= E) return;
#pragma unroll
    for (int t = 0; t < 16; ++t) {
        int e = base + t * 256 + threadIdx.x;
        if (e < E) atomicAdd(&rp[ei[E + e]], 1);
    }
}
// pass 2: one 1024-thread block per graph: chunked exclusive scan (in place),
// writes rp (final), rpw (working copy for placement), dinv, rp[n]=E.
__global__ __launch_bounds__(1024) void scan3_k(int* rp0, int* rp1, int* rp2,
                                                int* rw0, int* rw1, int* rw2,
                                                float* dv0, float* dv1) {
    __shared__ int wsum[16];
    __shared__ int scarry;
    int y = blockIdx.y;
    int n = (y == 2) ? 40000 : 20000;
    int E = (y == 2) ? 640000 : 320000;
    int* rp = (y == 0) ? rp0 : (y == 1) ? rp1 : rp2;
    int* rw = (y == 0) ? rw0 : (y == 1) ? rw1 : rw2;
    int tid = threadIdx.x, lane = tid & 63, wv = tid >> 6;
    if (tid == 0) scarry = 0;
    __syncthreads();
    for (int base = 0; base < n; base += 1024) {
        int i = base + tid;
        int v = (i < n) ? rp[i] : 0;
        int x = wscan_incl(v, lane);
        if (lane == 63) wsum[wv] = x;
        __syncthreads();
        int off = scarry;
#pragma unroll
        for (int w = 0; w < 16; ++w) off += (w < wv) ? wsum[w] : 0;
        int excl = off + x - v;
        if (i < n) {
            if (y == 0) dv0[i] = rsqrtf((float)(v + 1));
            else if (y == 1) dv1[i] = rsqrtf((float)(v + 1));
            rp[i] = excl;
            rw[i] = excl;
        }
        __syncthreads();
        if (tid == 0) {
            int tot = 0;
#pragma unroll
            for (int w = 0; w < 16; ++w) tot += wsum[w];
            scarry += tot;
        }
        __syncthreads();
    }
    if (tid == 0) rp[n] = E;
}
// pass 3: placement via atomic rank on working row-pointer copy
__global__ __launch_bounds__(256) void place3b_k(const int* e0, const int* e1, const int* e2,
                                                 int* rw0, int* rw1, int* rw2,
                                                 int* c0, int* c1, int* c2) {
    int y = blockIdx.y;
    const int* ei = (y == 0) ? e0 : (y == 1) ? e1 : e2;
    int E = (y == 2) ? 640000 : 320000;
    int* rw = (y == 0) ? rw0 : (y == 1) ? rw1 : rw2;
    int* col = (y == 0) ? c0 : (y == 1) ? c1 : c2;
    int base = blockIdx.x * 4096;
    if (base >= E) return;
#pragma unroll
    for (int t = 0; t < 16; ++t) {
        int e = base + t * 256 + threadIdx.x;
        if (e < E) {
            int s = ei[e], d = ei[E + e];
            int p = atomicAdd(&rw[d], 1);
            col[p] = s;
        }
    }
}

// ---------------- batched GCN GEMM (y = graph), LDS-free MR=1, frag-ordered B ----------
__global__ __launch_bounds__(256) void gemm2_k(const void* A0, const void* A1,
                                               const u16* __restrict__ Wtf0,
                                               const u16* __restrict__ Wtf1,
                                               const int* __restrict__ flagp,
                                               u16* __restrict__ C, int M) {
    int f = flagp[0];
    int y = blockIdx.y;
    const void* Aptr = y ? A1 : A0;
    const u16* Wtf = y ? Wtf1 : Wtf0;
    u16* Cp = C + (size_t)y * M * NF;
    int wave = threadIdx.x >> 6, lane = threadIdx.x & 63;
    int lr = lane & 15, q = lane >> 4;
    int arow = blockIdx.x * 64 + wave * 16 + lr;
    bool rok = arow < M;
    floatx4 acc[16];
#pragma unroll
    for (int nf = 0; nf < 16; ++nf) acc[nf] = (floatx4){0.f, 0.f, 0.f, 0.f};
    const u16* a16 = (const u16*)Aptr + (size_t)arow * NF;
    const float* a32 = (const float*)Aptr + (size_t)arow * NF;
#pragma unroll
    for (int ks = 0; ks < 8; ++ks) {
        int kk = ks * 32 + q * 8;
        union { u16 s[8]; uint4 u; short8 v; } a;
        if (!rok) {
            a.u = make_uint4(0u, 0u, 0u, 0u);
        } else if (f) {
            a.u = *(const uint4*)(a16 + kk);
            a.u.x = zap2(a.u.x); a.u.y = zap2(a.u.y);
            a.u.z = zap2(a.u.z); a.u.w = zap2(a.u.w);
        } else {
            float4 f0 = *(const float4*)(a32 + kk);
            float4 f1 = *(const float4*)(a32 + kk + 4);
            a.s[0] = f2bf(sane(f0.x)); a.s[1] = f2bf(sane(f0.y));
            a.s[2] = f2bf(sane(f0.z)); a.s[3] = f2bf(sane(f0.w));
            a.s[4] = f2bf(sane(f1.x)); a.s[5] = f2bf(sane(f1.y));
            a.s[6] = f2bf(sane(f1.z)); a.s[7] = f2bf(sane(f1.w));
        }
        const u16* bbase = Wtf + ks * 8192 + lane * 8;
#pragma unroll
        for (int nf = 0; nf < 16; ++nf) {
            short8 b = *(const short8*)(bbase + nf * 512);
            acc[nf] = __builtin_amdgcn_mfma_f32_16x16x32_bf16(a.v, b, acc[nf], 0, 0, 0);
        }
    }
#pragma unroll
    for (int nf = 0; nf < 16; ++nf) {
#pragma unroll
        for (int rr = 0; rr < 4; ++rr) {
            int gr = blockIdx.x * 64 + wave * 16 + q * 4 + rr;
            if (gr < M) Cp[(size_t)gr * NF + nf * 16 + lr] = f2bf(acc[nf][rr]);
        }
    }
}

// ---------------- GAT GEMM MR=1, fused scores epilogue (bf16 ws input) ----------------
__global__ __launch_bounds__(256) void gemm_gat_k(const u16* __restrict__ Aptr,
                                                  const u16* __restrict__ Wtf,
                                                  u16* __restrict__ C, int M,
                                                  const float* __restrict__ as_,
                                                  const float* __restrict__ ad_,
                                                  float* __restrict__ es,
                                                  float* __restrict__ ed) {
    int wave = threadIdx.x >> 6, lane = threadIdx.x & 63;
    int lr = lane & 15, q = lane >> 4;
    int arow = blockIdx.x * 64 + wave * 16 + lr;
    bool rok = arow < M;
    floatx4 acc[16];
#pragma unroll
    for (int nf = 0; nf < 16; ++nf) acc[nf] = (floatx4){0.f, 0.f, 0.f, 0.f};
    const u16* a16 = Aptr + (size_t)arow * NF;
#pragma unroll
    for (int ks = 0; ks < 8; ++ks) {
        int kk = ks * 32 + q * 8;
        union { uint4 u; short8 v; } a;
        a.u = rok ? *(const uint4*)(a16 + kk) : make_uint4(0u, 0u, 0u, 0u);
        const u16* bbase = Wtf + ks * 8192 + lane * 8;
#pragma unroll
        for (int nf = 0; nf < 16; ++nf) {
            short8 b = *(const short8*)(bbase + nf * 512);
            acc[nf] = __builtin_amdgcn_mfma_f32_16x16x32_bf16(a.v, b, acc[nf], 0, 0, 0);
        }
    }
#pragma unroll
    for (int nf = 0; nf < 16; ++nf) {
#pragma unroll
        for (int rr = 0; rr < 4; ++rr) {
            int gr = blockIdx.x * 64 + wave * 16 + q * 4 + rr;
            if (gr < M) C[(size_t)gr * NF + nf * 16 + lr] = f2bf(acc[nf][rr]);
        }
    }
    float asl[16], adl[16];
#pragma unroll
    for (int nf = 0; nf < 16; ++nf) { asl[nf] = as_[nf * 16 + lr]; adl[nf] = ad_[nf * 16 + lr]; }
#pragma unroll
    for (int rr = 0; rr < 4; ++rr) {
        float s1 = 0.f, s2 = 0.f;
#pragma unroll
        for (int nf = 0; nf < 16; ++nf) {
            s1 += acc[nf][rr] * asl[nf];
            s2 += acc[nf][rr] * adl[nf];
        }
#pragma unroll
        for (int o = 1; o < 16; o <<= 1) {
            s1 += __shfl_xor(s1, o, 64);
            s2 += __shfl_xor(s2, o, 64);
        }
        int gr = blockIdx.x * 64 + wave * 16 + q * 4 + rr;
        if (lr == 0 && gr < M) { es[gr] = s1; ed[gr] = s2; }
    }
}

// ---------------- batched GCN aggregation via CSR (y = graph) ----------------
// half-wave per edge, 4-edge unroll. Lane covers 8 channels via dwordx4.
__global__ __launch_bounds__(256) void gcn_csr2_k(const u16* __restrict__ h,
                                                  const int* rp0, const int* rp1,
                                                  const int* c0, const int* c1,
                                                  const float* dv0, const float* dv1,
                                                  const float* __restrict__ prm,
                                                  u16* __restrict__ out, int n) {
    int y = blockIdx.y;
    const int* rp = y ? rp1 : rp0;
    const int* col = y ? c1 : c0;
    const float* dinv = y ? dv1 : dv0;
    const float* b = prm + (y ? P_BAGG : P_BGCN);
    const u16* hb = h + (size_t)y * n * NF;
    u16* ob = out + (size_t)y * n * NF;
    int wave = threadIdx.x >> 6, lane = threadIdx.x & 63;
    int half = lane >> 5, sl = lane & 31;
    int i = blockIdx.x * 4 + wave;
    if (i >= n) return;
    int c = sl * 8;
    int beg = rp[i], end = rp[i + 1];
    float di = dinv[i];
    float acc[8] = {0.f, 0.f, 0.f, 0.f, 0.f, 0.f, 0.f, 0.f};
    float selfw = half ? 0.f : di * di;
    uint4 uv = *(const uint4*)(hb + (size_t)i * NF + c);
    fma8(uv, selfw, acc);
    int j = beg + half;
    for (; j + 6 < end; j += 8) {
        int s0 = col[j], s1 = col[j + 2], s2 = col[j + 4], s3 = col[j + 6];
        float n0 = dinv[s0] * di, n1 = dinv[s1] * di;
        float n2 = dinv[s2] * di, n3 = dinv[s3] * di;
        uint4 u0 = *(const uint4*)(hb + (size_t)s0 * NF + c);
        uint4 u1 = *(const uint4*)(hb + (size_t)s1 * NF + c);
        uint4 u2 = *(const uint4*)(hb + (size_t)s2 * NF + c);
        uint4 u3 = *(const uint4*)(hb + (size_t)s3 * NF + c);
        fma8(u0, n0, acc);
        fma8(u1, n1, acc);
        fma8(u2, n2, acc);
        fma8(u3, n3, acc);
    }
    for (; j < end; j += 2) {
        int s = col[j];
        float nr = dinv[s] * di;
        uint4 u = *(const uint4*)(hb + (size_t)s * NF + c);
        fma8(u, nr, acc);
    }
#pragma unroll
    for (int k = 0; k < 8; ++k) acc[k] += __shfl_xor(acc[k], 32, 64);
#pragma unroll
    for (int k = 0; k < 8; ++k) acc[k] += b[c + k];
    if (half == 0) st8h(ob + (size_t)i * NF + c, acc);
}

// ---------------- BN partial stats (no atomics) ----------------
__global__ void bn_stats2_k(const u16* __restrict__ x, int n,
                            float* __restrict__ psum, float* __restrict__ psq) {
    int y = blockIdx.y;
    int c = threadIdx.x;  // 256
    int r0 = blockIdx.x * 128;
    int rend = min(r0 + 128, n);
    const u16* xb = x + (size_t)y * n * NF;
    float s = 0.f, qq = 0.f;
    for (int r = r0; r < rend; ++r) {
        float v = bf2f(xb[(size_t)r * NF + c]);
        s += v; qq += v * v;
    }
    size_t o = (size_t)(y * PB + blockIdx.x) * 512 + c;
    psum[o] = s; psq[o] = qq;
}
// wave-per-channel finalize
__global__ void bn_fin2_k(const float* __restrict__ psum, const float* __restrict__ psq,
                          float* __restrict__ stg, int n, int nb) {
    int y = blockIdx.y;
    int wave = threadIdx.x >> 6, lane = threadIdx.x & 63;
    int c = blockIdx.x * 4 + wave;   // 256 channels, grid.x = 64
    float s = 0.f, qq = 0.f;
    for (int b = lane; b < nb; b += 64) {
        size_t o = (size_t)(y * PB + b) * 512 + c;
        s += psum[o]; qq += psq[o];
    }
    s = wredsum(s);
    qq = wredsum(qq);
    if (lane == 0) {
        float inv_n = 1.0f / (float)n;
        float mean = s * inv_n;
        float var = fmaxf(qq * inv_n - mean * mean, 0.f);
        stg[y * 512 + c] = mean;
        stg[y * 512 + 256 + c] = rsqrtf(var + EPSV);
    }
}
// vectorized: 8 values per thread (uint4 in / uint4 out)
__global__ void bn_apply2_k(const u16* __restrict__ x, const float* __restrict__ stg,
                            const float* __restrict__ prm, u16* __restrict__ out, int n) {
    int y = blockIdx.y;
    int t = blockIdx.x * 256 + threadIdx.x;
    if (t >= n * (NF / 8)) return;
    int c = (t & 31) * 8;
    const float* st = stg + y * 512;
    const float* g = prm + (y ? P_AGG1 : P_G1);
    const float* be = prm + (y ? P_AGBE1 : P_BE1);
    uint4 u = *(const uint4*)(x + (size_t)y * n * NF + (size_t)t * 8);
    float v[8];
    v[0] = __uint_as_float(u.x << 16); v[1] = __uint_as_float(u.x & 0xFFFF0000u);
    v[2] = __uint_as_float(u.y << 16); v[3] = __uint_as_float(u.y & 0xFFFF0000u);
    v[4] = __uint_as_float(u.z << 16); v[5] = __uint_as_float(u.z & 0xFFFF0000u);
    v[6] = __uint_as_float(u.w << 16); v[7] = __uint_as_float(u.w & 0xFFFF0000u);
    float r[8];
#pragma unroll
    for (int k = 0; k < 8; ++k) {
        int cc = c + k;
        float w = (v[k] - st[cc]) * st[256 + cc] * g[cc] + be[cc];
        r[k] = fmaxf(w, 0.f);
    }
    st8h(out + (size_t)y * n * NF + (size_t)t * 8, r);
}

// ---------------- single-pass fused GAT aggregation via CSR ----------------
// half-wave per edge, 4-edge unroll; es gathers issued alongside row loads.
__global__ __launch_bounds__(256) void gat_csr_k(const u16* __restrict__ h,
                                                 const int* __restrict__ rp,
                                                 const int* __restrict__ col,
                                                 const float* __restrict__ es,
                                                 const float* __restrict__ ed,
                                                 const float* __restrict__ b,
                                                 u16* __restrict__ out, int n,
                                                 int do_relu) {
    int wave = threadIdx.x >> 6, lane = threadIdx.x & 63;
    int half = lane >> 5, sl = lane & 31;
    int i = blockIdx.x * 4 + wave;
    if (i >= n) return;
    int beg = rp[i], end = rp[i + 1];
    float edi = ed[i];
    int c = sl * 8;
    float acc[8] = {0.f, 0.f, 0.f, 0.f, 0.f, 0.f, 0.f, 0.f};
    float ws = __expf(lrelu(es[i] + edi));
    float selfw = half ? 0.f : ws;
    float ssum = selfw;
    uint4 uv = *(const uint4*)(h + (size_t)i * NF + c);
    fma8(uv, selfw, acc);
    int j = beg + half;
    for (; j + 6 < end; j += 8) {
        int s0 = col[j], s1 = col[j + 2], s2 = col[j + 4], s3 = col[j + 6];
        float e0 = es[s0], e1 = es[s1], e2 = es[s2], e3 = es[s3];
        uint4 u0 = *(const uint4*)(h + (size_t)s0 * NF + c);
        uint4 u1 = *(const uint4*)(h + (size_t)s1 * NF + c);
        uint4 u2 = *(const uint4*)(h + (size_t)s2 * NF + c);
        uint4 u3 = *(const uint4*)(h + (size_t)s3 * NF + c);
        float a0 = __expf(lrelu(e0 + edi));
        float a1 = __expf(lrelu(e1 + edi));
        float a2 = __expf(lrelu(e2 + edi));
        float a3 = __expf(lrelu(e3 + edi));
        ssum += (a0 + a1) + (a2 + a3);
        fma8(u0, a0, acc);
        fma8(u1, a1, acc);
        fma8(u2, a2, acc);
        fma8(u3, a3, acc);
    }
    for (; j < end; j += 2) {
        int s = col[j];
        float a = __expf(lrelu(es[s] + edi));
        uint4 u = *(const uint4*)(h + (size_t)s * NF + c);
        ssum += a;
        fma8(u, a, acc);
    }
    ssum += __shfl_xor(ssum, 32, 64);
#pragma unroll
    for (int k = 0; k < 8; ++k) acc[k] += __shfl_xor(acc[k], 32, 64);
    float inv = 1.0f / ssum;
#pragma unroll
    for (int k = 0; k < 8; ++k) {
        acc[k] = b[c + k] + acc[k] * inv;
        if (do_relu) acc[k] = fmaxf(acc[k], 0.f);
    }
    if (half == 0) st8h(out + (size_t)i * NF + c, acc);
}

// ---------------- batched final-stage BN stats over cat(x,h) (512 ch) ----------------
__global__ void bn_stats_cat2_k(const u16* __restrict__ xp, const u16* __restrict__ hp,
                                int n, float* __restrict__ psum, float* __restrict__ psq) {
    int y = blockIdx.y;
    int c = threadIdx.x;  // 512
    int r0 = blockIdx.x * 128;
    int rend = min(r0 + 128, n);
    const u16* src = ((c < 256) ? xp : hp) + (size_t)y * n * NF;
    int cc = c & 255;
    float s = 0.f, qq = 0.f;
    for (int r = r0; r < rend; ++r) {
        float v = bf2f(src[(size_t)r * NF + cc]);
        s += v; qq += v * v;
    }
    size_t o = (size_t)(y * PB + blockIdx.x) * 512 + c;
    psum[o] = s; psq[o] = qq;
}
// wave-per-channel finalize (512 channels)
__global__ void bn_fin_cat2_k(const float* __restrict__ psum, const float* __restrict__ psq,
                              float* __restrict__ stc, int n, int nb) {
    int y = blockIdx.y;
    int wave = threadIdx.x >> 6, lane = threadIdx.x & 63;
    int c = blockIdx.x * 4 + wave;   // 512 channels, grid.x = 128
    float s = 0.f, qq = 0.f;
    for (int b = lane; b < nb; b += 64) {
        size_t o = (size_t)(y * PB + b) * 512 + c;
        s += psum[o]; qq += psq[o];
    }
    s = wredsum(s);
    qq = wredsum(qq);
    if (lane == 0) {
        float inv_n = 1.0f / (float)n;
        float mean = s * inv_n;
        float var = fmaxf(qq * inv_n - mean * mean, 0.f);
        stc[y * 1024 + c] = mean;
        stc[y * 1024 + 512 + c] = rsqrtf(var + EPSV);
    }
}
__global__ void final2_k(const u16* __restrict__ xp, const u16* __restrict__ hp,
                         const float* __restrict__ stc, const float* __restrict__ prm,
                         float* __restrict__ out, int n) {
    int y = blockIdx.y;
    int wave = threadIdx.x >> 6, lane = threadIdx.x & 63;
    int i = blockIdx.x * 4 + wave;
    if (i >= n) return;
    const float* st = stc + y * 1024;
    const float* g = prm + (y ? P_AGG2 : P_G2);
    const float* be = prm + (y ? P_AGBE2 : P_BE2);
    const float* w = prm + (y ? P_WAGFC : P_WFC);
    float bias = prm[y ? P_BAGFC : P_BFC];
    const u16* src = (((lane < 32) ? xp : hp) + (size_t)y * n * NF) + (size_t)i * NF
                     + (lane < 32 ? lane * 8 : (lane - 32) * 8);
    uint4 u = *(const uint4*)src;
    float vv[8];
    vv[0] = bf2f((u16)(u.x & 0xFFFFu)); vv[1] = bf2f((u16)(u.x >> 16));
    vv[2] = bf2f((u16)(u.y & 0xFFFFu)); vv[3] = bf2f((u16)(u.y >> 16));
    vv[4] = bf2f((u16)(u.z & 0xFFFFu)); vv[5] = bf2f((u16)(u.z >> 16));
    vv[6] = bf2f((u16)(u.w & 0xFFFFu)); vv[7] = bf2f((u16)(u.w >> 16));
    int c0 = lane * 8;
    float acc = 0.f;
#pragma unroll
    for (int j = 0; j < 8; ++j) {
        int c = c0 + j;
        float v = (vv[j] - st[c]) * st[512 + c] * g[c] + be[c];
        v = fmaxf(v, 0.f);
        acc += v * w[c];
    }
    acc = wredsum(acc);
    if (lane == 0) out[(size_t)y * 20000 + i] = acc + bias;
}

// ---------------- host ----------------
extern "C" void kernel_launch(void* const* d_in, const int* in_sizes, int n_in,
                              void* d_out, int out_size, void* d_ws, size_t ws_size,
                              hipStream_t stream) {
    const void* x_ab = d_in[0];
    const void* x_ag = d_in[1];
    const int* e_ab = (const int*)d_in[26];
    const int* e_ag = (const int*)d_in[27];
    const int* e_d = (const int*)d_in[28];

    const int NAB = 20000, NT = 40000;
    const int EAB = 320000, EAG = 320000, ED = 640000;

    u16* hcat = (u16*)d_ws;                     // NT*NF u16
    u16* bufA = hcat + (size_t)NT * NF;         // NT*NF u16
    u16* bufB = bufA + (size_t)NT * NF;         // NT*NF u16
    u16* wt4 = bufB + (size_t)NT * NF;          // 4*65536 u16
    float* dv0 = (float*)(wt4 + 4 * 65536);     // NAB
    float* dv1 = dv0 + NAB;                     // NAB
    float* es = dv1 + NAB;                      // NT
    float* edv = es + NT;                       // NT
    float* stg2 = edv + NT;                     // 1024
    float* stc = stg2 + 1024;                   // 2048
    float* psum = stc + 2048;                   // 2*PB*512
    float* psq = psum + 2 * PB * 512;           // 2*PB*512
    float* prm = psq + 2 * PB * 512;            // 8192
    int* flag = (int*)(prm + 8192);             // 16
    int* rp_ab = flag + 16;                     // NAB+1  } contiguous zero range
    int* rp_ag = rp_ab + NAB + 1;               // NAB+1  }
    int* rp_d = rp_ag + NAB + 1;                // NT+1   }
    int* rw_ab = rp_d + NT + 1;                 // NAB+1 (working copies, no zeroing)
    int* rw_ag = rw_ab + NAB + 1;               // NAB+1
    int* rw_d = rw_ag + NAB + 1;                // NT+1
    int* col_ab = rw_d + NT + 1;                // EAB
    int* col_ag = col_ab + EAB;                 // EAG
    int* col_d = col_ag + EAG;                  // ED

    u16* wt_gcn = wt4;
    u16* wt_aggcn = wt4 + 65536;
    u16* wt_gat = wt4 + 2 * 65536;
    u16* wt_gat2 = wt4 + 3 * 65536;

    dim3 t256(256), t512(512), t1024(1024);
    const int nbg = (NAB + 127) / 128;   // 157 bn partial blocks per graph
    const int nzero = (NAB + 1) * 2 + (NT + 1);   // rp_ab + rp_ag + rp_d

    detect_k<<<dim3(1), t256, 0, stream>>>((const u16*)x_ab, flag);
    prep_k<<<dim3(1049), t256, 0, stream>>>(
        d_in[2], d_in[6], d_in[10], d_in[14],
        d_in[3], d_in[4], d_in[5], d_in[7], d_in[8], d_in[9],
        d_in[11], d_in[12], d_in[13], d_in[15], d_in[16], d_in[17],
        d_in[22], d_in[23], d_in[24], d_in[18], d_in[19], d_in[20],
        d_in[25], d_in[21], wt4, prm, rp_ab, nzero, flag);

    // CSR build v2 (3 dispatches)
    cnt3_k<<<dim3(157, 3), t256, 0, stream>>>(e_ab, e_ag, e_d, rp_ab, rp_ag, rp_d);
    scan3_k<<<dim3(1, 3), t1024, 0, stream>>>(rp_ab, rp_ag, rp_d,
                                              rw_ab, rw_ag, rw_d, dv0, dv1);
    place3b_k<<<dim3(157, 3), t256, 0, stream>>>(e_ab, e_ag, e_d,
                                                 rw_ab, rw_ag, rw_d,
                                                 col_ab, col_ag, col_d);

    // batched GCN stage (5 dispatches)
    gemm2_k<<<dim3((NAB + 63) / 64, 2), t256, 0, stream>>>(x_ab, x_ag, wt_gcn, wt_aggcn,
                                                           flag, bufA, NAB);
    gcn_csr2_k<<<dim3((NAB + 3) / 4, 2), t256, 0, stream>>>(bufA, rp_ab, rp_ag,
                                                            col_ab, col_ag, dv0, dv1,
                                                            prm, bufB, NAB);
    bn_stats2_k<<<dim3(nbg, 2), t256, 0, stream>>>(bufB, NAB, psum, psq);
    bn_fin2_k<<<dim3(64, 2), t256, 0, stream>>>(psum, psq, stg2, NAB, nbg);
    bn_apply2_k<<<dim3((NAB * NF / 8 + 255) / 256, 2), t256, 0, stream>>>(bufB, stg2, prm,
                                                                          hcat, NAB);

    // GAT layer 1 (2 dispatches)
    gemm_gat_k<<<dim3((NT + 63) / 64), t256, 0, stream>>>(hcat, wt_gat, bufA, NT,
                                                          prm + P_ASRC, prm + P_ADST,
                                                          es, edv);
    gat_csr_k<<<dim3((NT + 3) / 4), t256, 0, stream>>>(bufA, rp_d, col_d, es, edv,
                                                       prm + P_BGAT, bufB, NT, 1);
    // GAT layer 2 (2 dispatches)
    gemm_gat_k<<<dim3((NT + 63) / 64), t256, 0, stream>>>(bufB, wt_gat2, bufA, NT,
                                                          prm + P_ASRC2, prm + P_ADST2,
                                                          es, edv);
    gat_csr_k<<<dim3((NT + 3) / 4), t256, 0, stream>>>(bufA, rp_d, col_d, es, edv,
                                                       prm + P_BGAT2, bufB, NT, 0);

    // batched final stage (3 dispatches)
    bn_stats_cat2_k<<<dim3(nbg, 2), t512, 0, stream>>>(bufB, hcat, NAB, psum, psq);
    bn_fin_cat2_k<<<dim3(128, 2), t256, 0, stream>>>(psum, psq, stc, NAB, nbg);
    final2_k<<<dim3((NAB + 3) / 4, 2), t256, 0, stream>>>(bufB, hcat, stc, prm,
                                                          (float*)d_out, NAB);
}

// Round 9
// 506.667 us; speedup vs baseline: 2.4940x; 1.2736x over previous
//
#include <hip/hip_runtime.h>
#include <hip/hip_bf16.h>
#include <stdint.h>

#define NF 256
#define EPSV 1e-5f
#define PB 160     // max bn partial blocks
#define MAXBUK 160 // max coarse buckets (dst>>8): 157 for NT=40000

typedef unsigned short u16;
typedef unsigned int u32;
typedef short short8 __attribute__((ext_vector_type(8)));
typedef float floatx4 __attribute__((ext_vector_type(4)));

// param block offsets (floats): 12 x 256, then 6 x 512, then 2 x 1
#define P_BGCN 0
#define P_G1 256
#define P_BE1 512
#define P_BAGG 768
#define P_AGG1 1024
#define P_AGBE1 1280
#define P_ASRC 1536
#define P_ADST 1792
#define P_BGAT 2048
#define P_ASRC2 2304
#define P_ADST2 2560
#define P_BGAT2 2816
#define P_G2 3072
#define P_BE2 3584
#define P_WFC 4096
#define P_AGG2 4608
#define P_AGBE2 5120
#define P_WAGFC 5632
#define P_BFC 6144
#define P_BAGFC 6145

__device__ __forceinline__ float bf2f(u16 u) {
    union { unsigned int i; float f; } v; v.i = ((unsigned int)u) << 16; return v.f;
}
__device__ __forceinline__ u16 f2bf(float f) {
    unsigned int x = __float_as_uint(f);
    unsigned int r = x + 0x7fffu + ((x >> 16) & 1u);
    return (u16)(r >> 16);
}
__device__ __forceinline__ float sane(float f) {
    return (f == f && fabsf(f) < 1e30f) ? f : 0.f;
}
__device__ __forceinline__ unsigned int zap2(unsigned int w) {
    if ((w & 0x00007F80u) == 0x00007F80u) w &= 0xFFFF0000u;
    if ((w & 0x7F800000u) == 0x7F800000u) w &= 0x0000FFFFu;
    return w;
}
__device__ __forceinline__ float lrelu(float x) { return x > 0.f ? x : 0.2f * x; }

__device__ __forceinline__ float4 ld4h(const u16* p) {
    uint2 u = *(const uint2*)p;
    float4 r;
    r.x = bf2f((u16)(u.x & 0xFFFFu)); r.y = bf2f((u16)(u.x >> 16));
    r.z = bf2f((u16)(u.y & 0xFFFFu)); r.w = bf2f((u16)(u.y >> 16));
    return r;
}
__device__ __forceinline__ void st4h(u16* p, float4 v) {
    uint2 u;
    u.x = (unsigned)f2bf(v.x) | ((unsigned)f2bf(v.y) << 16);
    u.y = (unsigned)f2bf(v.z) | ((unsigned)f2bf(v.w) << 16);
    *(uint2*)p = u;
}

// 8 bf16 (uint4) -> acc[k] += a * h[k], unpack is 1 VALU per value
__device__ __forceinline__ void fma8(const uint4 u, float a, float* acc) {
    acc[0] = fmaf(__uint_as_float(u.x << 16), a, acc[0]);
    acc[1] = fmaf(__uint_as_float(u.x & 0xFFFF0000u), a, acc[1]);
    acc[2] = fmaf(__uint_as_float(u.y << 16), a, acc[2]);
    acc[3] = fmaf(__uint_as_float(u.y & 0xFFFF0000u), a, acc[3]);
    acc[4] = fmaf(__uint_as_float(u.z << 16), a, acc[4]);
    acc[5] = fmaf(__uint_as_float(u.z & 0xFFFF0000u), a, acc[5]);
    acc[6] = fmaf(__uint_as_float(u.w << 16), a, acc[6]);
    acc[7] = fmaf(__uint_as_float(u.w & 0xFFFF0000u), a, acc[7]);
}
__device__ __forceinline__ void st8h(u16* p, const float* v) {
    uint4 u;
    u.x = (u32)f2bf(v[0]) | ((u32)f2bf(v[1]) << 16);
    u.y = (u32)f2bf(v[2]) | ((u32)f2bf(v[3]) << 16);
    u.z = (u32)f2bf(v[4]) | ((u32)f2bf(v[5]) << 16);
    u.w = (u32)f2bf(v[6]) | ((u32)f2bf(v[7]) << 16);
    *(uint4*)p = u;
}

__device__ __forceinline__ float wredsum(float v) {
#pragma unroll
    for (int o = 32; o > 0; o >>= 1) v += __shfl_xor(v, o, 64);
    return v;
}
__device__ __forceinline__ int wscan_incl(int x, int lane) {
#pragma unroll
    for (int o = 1; o < 64; o <<= 1) {
        int t = __shfl_up(x, o, 64);
        if (lane >= o) x += t;
    }
    return x;
}

// ---------------- dtype detect ----------------
__global__ void detect_k(const u16* __restrict__ x, int* __restrict__ flag) {
    __shared__ int cnt;
    if (threadIdx.x == 0) cnt = 0;
    __syncthreads();
    int c = 0;
#pragma unroll
    for (int k = 0; k < 4; ++k) {
        unsigned int u = x[2 * (threadIdx.x + 256 * k)];
        int e = (int)((u >> 7) & 0xFFu);
        if (u == 0u || (e >= 100 && e <= 140)) c++;
    }
    atomicAdd(&cnt, c);
    __syncthreads();
    if (threadIdx.x == 0) flag[0] = (cnt >= 512) ? 1 : 0;
}

// ---------------- prep: weight fragment-pack + param cvt + counter zero ----------------
__global__ void prep_k(const void* w0, const void* w1, const void* w2, const void* w3,
                       const void* p0, const void* p1, const void* p2, const void* p3,
                       const void* p4, const void* p5, const void* p6, const void* p7,
                       const void* p8, const void* p9, const void* p10, const void* p11,
                       const void* p12, const void* p13, const void* p14, const void* p15,
                       const void* p16, const void* p17, const void* p18, const void* p19,
                       u16* __restrict__ wtf, float* __restrict__ prm,
                       int* __restrict__ zb, int nz,
                       const int* __restrict__ flagp) {
    int f = flagp[0];
    int idx = blockIdx.x * 256 + threadIdx.x;
    if (idx < nz) zb[idx] = 0;
    if (idx < 262144) {
        const void* ws[4] = {w0, w1, w2, w3};
        int wi = idx >> 16;
        int rest = idx & 65535;
        int j = rest & 7;
        int lr = (rest >> 3) & 15;
        int q = (rest >> 7) & 3;
        int nf = (rest >> 9) & 15;
        int ks = (rest >> 13) & 7;
        int n = nf * 16 + lr;
        int k = ks * 32 + q * 8 + j;
        const void* W = ws[wi];
        u16 v;
        if (f) {
            v = ((const u16*)W)[k * NF + n];
            if ((v & 0x7F80u) == 0x7F80u) v = 0;
        } else {
            v = f2bf(sane(((const float*)W)[k * NF + n]));
        }
        wtf[idx] = v;
        return;
    }
    int pidx = idx - 262144;
    if (pidx >= 6146) return;
    const void* ptrs[20] = {p0, p1, p2, p3, p4, p5, p6, p7, p8, p9,
                            p10, p11, p12, p13, p14, p15, p16, p17, p18, p19};
    int t, j;
    if (pidx < 3072) { t = pidx >> 8; j = pidx & 255; }
    else if (pidx < 6144) { t = 12 + ((pidx - 3072) >> 9); j = (pidx - 3072) & 511; }
    else { t = 18 + (pidx - 6144); j = 0; }
    float v = f ? bf2f(((const u16*)ptrs[t])[j]) : ((const float*)ptrs[t])[j];
    prm[pidx] = sane(v);
}

// ---------------- bucket-level CSR build (y = graph: 0=ab, 1=ag, 2=d) ----------------
// pass 0: coarse bucket counts via LDS histogram (one global atomic per block,bucket)
__global__ __launch_bounds__(256) void bucket_cnt3_k(const int* e0, const int* e1,
                                                     const int* e2,
                                                     int* __restrict__ gbcnt) {
    int y = blockIdx.y;
    const int* ei = (y == 0) ? e0 : (y == 1) ? e1 : e2;
    int E = (y == 2) ? 640000 : 320000;
    int n = (y == 2) ? 40000 : 20000;
    int nbuk = (n + 255) >> 8;
    int base = blockIdx.x * 4096;
    if (base >= E) return;
    __shared__ int l[MAXBUK];
    if (threadIdx.x < nbuk) l[threadIdx.x] = 0;
    __syncthreads();
#pragma unroll
    for (int t = 0; t < 16; ++t) {
        int e = base + t * 256 + threadIdx.x;
        if (e < E) atomicAdd(&l[ei[E + e] >> 8], 1);
    }
    __syncthreads();
    if (threadIdx.x < nbuk) {
        int c = l[threadIdx.x];
        if (c) atomicAdd(&gbcnt[y * MAXBUK + threadIdx.x], c);
    }
}
// pass 1: single block per graph scans bucket counts -> bucket bases bb; rp[n]=E
__global__ __launch_bounds__(256) void bucket_scan3_k(const int* __restrict__ gbcnt,
                                                      int* __restrict__ bb,
                                                      int* rp0, int* rp1, int* rp2) {
    __shared__ int wp[4];
    int y = blockIdx.y;
    int n = (y == 2) ? 40000 : 20000;
    int E = (y == 2) ? 640000 : 320000;
    int nbuk = (n + 255) >> 8;
    int* rp = (y == 0) ? rp0 : (y == 1) ? rp1 : rp2;
    int lane = threadIdx.x & 63, wave = threadIdx.x >> 6;
    int v = (threadIdx.x < nbuk) ? gbcnt[y * MAXBUK + threadIdx.x] : 0;
    int x = wscan_incl(v, lane);
    if (lane == 63) wp[wave] = x;
    __syncthreads();
    int off = 0;
#pragma unroll
    for (int w = 0; w < 4; ++w) off += (w < wave) ? wp[w] : 0;
    if (threadIdx.x < nbuk) bb[y * (MAXBUK + 1) + threadIdx.x] = off + x - v;
    if (threadIdx.x == 0) {
        bb[y * (MAXBUK + 1) + nbuk] = E;
        rp[n] = E;
    }
}
// pass 2: bucket-binned staging. Record = src | (dst&255)<<16.
__global__ __launch_bounds__(256) void bin3_k(const int* e0, const int* e1, const int* e2,
                                              const int* __restrict__ bb,
                                              int* __restrict__ gcur,
                                              u32* s0, u32* s1, u32* s2) {
    int y = blockIdx.y;
    const int* ei = (y == 0) ? e0 : (y == 1) ? e1 : e2;
    u32* stg = (y == 0) ? s0 : (y == 1) ? s1 : s2;
    int E = (y == 2) ? 640000 : 320000;
    int n = (y == 2) ? 40000 : 20000;
    int nbuk = (n + 255) >> 8;
    int base = blockIdx.x * 4096;
    if (base >= E) return;
    __shared__ int lcnt[MAXBUK];
    __shared__ int lbase[MAXBUK];
    if (threadIdx.x < nbuk) lcnt[threadIdx.x] = 0;
    __syncthreads();
#pragma unroll
    for (int t = 0; t < 16; ++t) {
        int e = base + t * 256 + threadIdx.x;
        if (e < E) atomicAdd(&lcnt[ei[E + e] >> 8], 1);
    }
    __syncthreads();
    if (threadIdx.x < nbuk) {
        int cnt = lcnt[threadIdx.x];
        int g = cnt ? atomicAdd(&gcur[y * MAXBUK + threadIdx.x], cnt) : 0;
        lbase[threadIdx.x] = bb[y * (MAXBUK + 1) + threadIdx.x] + g;
        lcnt[threadIdx.x] = 0;
    }
    __syncthreads();
#pragma unroll
    for (int t = 0; t < 16; ++t) {
        int e = base + t * 256 + threadIdx.x;
        if (e < E) {
            int s = ei[e], d = ei[E + e];
            int b = d >> 8;
            int r = atomicAdd(&lcnt[b], 1);
            stg[lbase[b] + r] = (u32)s | ((u32)(d & 255) << 16);
        }
    }
}
// pass 3: one block per bucket: per-dst counts (LDS) -> rp + dinv + ranked col placement
__global__ __launch_bounds__(256) void place3_k(const u32* s0, const u32* s1, const u32* s2,
                                                const int* __restrict__ bb,
                                                int* rp0, int* rp1, int* rp2,
                                                float* dv0, float* dv1,
                                                int* c0, int* c1, int* c2) {
    __shared__ int wp[4];
    __shared__ int lcnt[256];
    __shared__ int lrp[256];
    int y = blockIdx.y;
    int b = blockIdx.x;
    int n = (y == 2) ? 40000 : 20000;
    int nbuk = (n + 255) >> 8;
    if (b >= nbuk) return;
    const u32* stg = (y == 0) ? s0 : (y == 1) ? s1 : s2;
    int* rp = (y == 0) ? rp0 : (y == 1) ? rp1 : rp2;
    int* col = (y == 0) ? c0 : (y == 1) ? c1 : c2;
    int d0 = b << 8;
    int dn = min(256, n - d0);
    int base = bb[y * (MAXBUK + 1) + b];
    int endv = bb[y * (MAXBUK + 1) + b + 1];
    lcnt[threadIdx.x] = 0;
    __syncthreads();
    for (int j = base + threadIdx.x; j < endv; j += 256)
        atomicAdd(&lcnt[stg[j] >> 16], 1);
    __syncthreads();
    // exclusive 256-scan of lcnt -> lrp (+base)
    int lane = threadIdx.x & 63, wave = threadIdx.x >> 6;
    int v = lcnt[threadIdx.x];
    int x = wscan_incl(v, lane);
    if (lane == 63) wp[wave] = x;
    __syncthreads();
    int off = 0;
#pragma unroll
    for (int w = 0; w < 4; ++w) off += (w < wave) ? wp[w] : 0;
    int excl = base + off + x - v;
    lrp[threadIdx.x] = excl;
    if (threadIdx.x < dn) {
        rp[d0 + threadIdx.x] = excl;
        if (y == 0) dv0[d0 + threadIdx.x] = rsqrtf((float)(v + 1));
        else if (y == 1) dv1[d0 + threadIdx.x] = rsqrtf((float)(v + 1));
    }
    lcnt[threadIdx.x] = 0;
    __syncthreads();
    for (int j = base + threadIdx.x; j < endv; j += 256) {
        u32 rec = stg[j];
        int dl = (int)(rec >> 16);
        int s = (int)(rec & 0xFFFFu);
        int r = atomicAdd(&lcnt[dl], 1);
        col[lrp[dl] + r] = s;
    }
}

// ---------------- batched GCN GEMM (y = graph), LDS-free MR=1, frag-ordered B ----------
__global__ __launch_bounds__(256) void gemm2_k(const void* A0, const void* A1,
                                               const u16* __restrict__ Wtf0,
                                               const u16* __restrict__ Wtf1,
                                               const int* __restrict__ flagp,
                                               u16* __restrict__ C, int M) {
    int f = flagp[0];
    int y = blockIdx.y;
    const void* Aptr = y ? A1 : A0;
    const u16* Wtf = y ? Wtf1 : Wtf0;
    u16* Cp = C + (size_t)y * M * NF;
    int wave = threadIdx.x >> 6, lane = threadIdx.x & 63;
    int lr = lane & 15, q = lane >> 4;
    int arow = blockIdx.x * 64 + wave * 16 + lr;
    bool rok = arow < M;
    floatx4 acc[16];
#pragma unroll
    for (int nf = 0; nf < 16; ++nf) acc[nf] = (floatx4){0.f, 0.f, 0.f, 0.f};
    const u16* a16 = (const u16*)Aptr + (size_t)arow * NF;
    const float* a32 = (const float*)Aptr + (size_t)arow * NF;
#pragma unroll
    for (int ks = 0; ks < 8; ++ks) {
        int kk = ks * 32 + q * 8;
        union { u16 s[8]; uint4 u; short8 v; } a;
        if (!rok) {
            a.u = make_uint4(0u, 0u, 0u, 0u);
        } else if (f) {
            a.u = *(const uint4*)(a16 + kk);
            a.u.x = zap2(a.u.x); a.u.y = zap2(a.u.y);
            a.u.z = zap2(a.u.z); a.u.w = zap2(a.u.w);
        } else {
            float4 f0 = *(const float4*)(a32 + kk);
            float4 f1 = *(const float4*)(a32 + kk + 4);
            a.s[0] = f2bf(sane(f0.x)); a.s[1] = f2bf(sane(f0.y));
            a.s[2] = f2bf(sane(f0.z)); a.s[3] = f2bf(sane(f0.w));
            a.s[4] = f2bf(sane(f1.x)); a.s[5] = f2bf(sane(f1.y));
            a.s[6] = f2bf(sane(f1.z)); a.s[7] = f2bf(sane(f1.w));
        }
        const u16* bbase = Wtf + ks * 8192 + lane * 8;
#pragma unroll
        for (int nf = 0; nf < 16; ++nf) {
            short8 b = *(const short8*)(bbase + nf * 512);
            acc[nf] = __builtin_amdgcn_mfma_f32_16x16x32_bf16(a.v, b, acc[nf], 0, 0, 0);
        }
    }
#pragma unroll
    for (int nf = 0; nf < 16; ++nf) {
#pragma unroll
        for (int rr = 0; rr < 4; ++rr) {
            int gr = blockIdx.x * 64 + wave * 16 + q * 4 + rr;
            if (gr < M) Cp[(size_t)gr * NF + nf * 16 + lr] = f2bf(acc[nf][rr]);
        }
    }
}

// ---------------- GAT GEMM MR=1, fused scores epilogue (bf16 ws input) ----------------
__global__ __launch_bounds__(256) void gemm_gat_k(const u16* __restrict__ Aptr,
                                                  const u16* __restrict__ Wtf,
                                                  u16* __restrict__ C, int M,
                                                  const float* __restrict__ as_,
                                                  const float* __restrict__ ad_,
                                                  float* __restrict__ es,
                                                  float* __restrict__ ed) {
    int wave = threadIdx.x >> 6, lane = threadIdx.x & 63;
    int lr = lane & 15, q = lane >> 4;
    int arow = blockIdx.x * 64 + wave * 16 + lr;
    bool rok = arow < M;
    floatx4 acc[16];
#pragma unroll
    for (int nf = 0; nf < 16; ++nf) acc[nf] = (floatx4){0.f, 0.f, 0.f, 0.f};
    const u16* a16 = Aptr + (size_t)arow * NF;
#pragma unroll
    for (int ks = 0; ks < 8; ++ks) {
        int kk = ks * 32 + q * 8;
        union { uint4 u; short8 v; } a;
        a.u = rok ? *(const uint4*)(a16 + kk) : make_uint4(0u, 0u, 0u, 0u);
        const u16* bbase = Wtf + ks * 8192 + lane * 8;
#pragma unroll
        for (int nf = 0; nf < 16; ++nf) {
            short8 b = *(const short8*)(bbase + nf * 512);
            acc[nf] = __builtin_amdgcn_mfma_f32_16x16x32_bf16(a.v, b, acc[nf], 0, 0, 0);
        }
    }
#pragma unroll
    for (int nf = 0; nf < 16; ++nf) {
#pragma unroll
        for (int rr = 0; rr < 4; ++rr) {
            int gr = blockIdx.x * 64 + wave * 16 + q * 4 + rr;
            if (gr < M) C[(size_t)gr * NF + nf * 16 + lr] = f2bf(acc[nf][rr]);
        }
    }
    float asl[16], adl[16];
#pragma unroll
    for (int nf = 0; nf < 16; ++nf) { asl[nf] = as_[nf * 16 + lr]; adl[nf] = ad_[nf * 16 + lr]; }
#pragma unroll
    for (int rr = 0; rr < 4; ++rr) {
        float s1 = 0.f, s2 = 0.f;
#pragma unroll
        for (int nf = 0; nf < 16; ++nf) {
            s1 += acc[nf][rr] * asl[nf];
            s2 += acc[nf][rr] * adl[nf];
        }
#pragma unroll
        for (int o = 1; o < 16; o <<= 1) {
            s1 += __shfl_xor(s1, o, 64);
            s2 += __shfl_xor(s2, o, 64);
        }
        int gr = blockIdx.x * 64 + wave * 16 + q * 4 + rr;
        if (lr == 0 && gr < M) { es[gr] = s1; ed[gr] = s2; }
    }
}

// ---------------- batched GCN aggregation via CSR (y = graph) ----------------
// half-wave per edge, 4-edge unroll. Lane covers 8 channels via dwordx4.
__global__ __launch_bounds__(256) void gcn_csr2_k(const u16* __restrict__ h,
                                                  const int* rp0, const int* rp1,
                                                  const int* c0, const int* c1,
                                                  const float* dv0, const float* dv1,
                                                  const float* __restrict__ prm,
                                                  u16* __restrict__ out, int n) {
    int y = blockIdx.y;
    const int* rp = y ? rp1 : rp0;
    const int* col = y ? c1 : c0;
    const float* dinv = y ? dv1 : dv0;
    const float* b = prm + (y ? P_BAGG : P_BGCN);
    const u16* hb = h + (size_t)y * n * NF;
    u16* ob = out + (size_t)y * n * NF;
    int wave = threadIdx.x >> 6, lane = threadIdx.x & 63;
    int half = lane >> 5, sl = lane & 31;
    int i = blockIdx.x * 4 + wave;
    if (i >= n) return;
    int c = sl * 8;
    int beg = rp[i], end = rp[i + 1];
    float di = dinv[i];
    float acc[8] = {0.f, 0.f, 0.f, 0.f, 0.f, 0.f, 0.f, 0.f};
    // self term only on half 0 (cross-half sum would double it otherwise)
    float selfw = half ? 0.f : di * di;
    uint4 uv = *(const uint4*)(hb + (size_t)i * NF + c);
    fma8(uv, selfw, acc);
    int j = beg + half;
    for (; j + 6 < end; j += 8) {
        int s0 = col[j], s1 = col[j + 2], s2 = col[j + 4], s3 = col[j + 6];
        float n0 = dinv[s0] * di, n1 = dinv[s1] * di;
        float n2 = dinv[s2] * di, n3 = dinv[s3] * di;
        uint4 u0 = *(const uint4*)(hb + (size_t)s0 * NF + c);
        uint4 u1 = *(const uint4*)(hb + (size_t)s1 * NF + c);
        uint4 u2 = *(const uint4*)(hb + (size_t)s2 * NF + c);
        uint4 u3 = *(const uint4*)(hb + (size_t)s3 * NF + c);
        fma8(u0, n0, acc);
        fma8(u1, n1, acc);
        fma8(u2, n2, acc);
        fma8(u3, n3, acc);
    }
    for (; j < end; j += 2) {
        int s = col[j];
        float nr = dinv[s] * di;
        uint4 u = *(const uint4*)(hb + (size_t)s * NF + c);
        fma8(u, nr, acc);
    }
#pragma unroll
    for (int k = 0; k < 8; ++k) acc[k] += __shfl_xor(acc[k], 32, 64);
#pragma unroll
    for (int k = 0; k < 8; ++k) acc[k] += b[c + k];
    if (half == 0) st8h(ob + (size_t)i * NF + c, acc);
}

// ---------------- BN partial stats (no atomics) ----------------
__global__ void bn_stats2_k(const u16* __restrict__ x, int n,
                            float* __restrict__ psum, float* __restrict__ psq) {
    int y = blockIdx.y;
    int c = threadIdx.x;  // 256
    int r0 = blockIdx.x * 128;
    int rend = min(r0 + 128, n);
    const u16* xb = x + (size_t)y * n * NF;
    float s = 0.f, qq = 0.f;
    for (int r = r0; r < rend; ++r) {
        float v = bf2f(xb[(size_t)r * NF + c]);
        s += v; qq += v * v;
    }
    size_t o = (size_t)(y * PB + blockIdx.x) * 512 + c;
    psum[o] = s; psq[o] = qq;
}
// wave-per-channel finalize: lanes stride over partial blocks, shfl tree reduce.
__global__ void bn_fin2_k(const float* __restrict__ psum, const float* __restrict__ psq,
                          float* __restrict__ stg, int n, int nb) {
    int y = blockIdx.y;
    int wave = threadIdx.x >> 6, lane = threadIdx.x & 63;
    int c = blockIdx.x * 4 + wave;   // 256 channels, grid.x = 64
    float s = 0.f, qq = 0.f;
    for (int b = lane; b < nb; b += 64) {
        size_t o = (size_t)(y * PB + b) * 512 + c;
        s += psum[o]; qq += psq[o];
    }
    s = wredsum(s);
    qq = wredsum(qq);
    if (lane == 0) {
        float inv_n = 1.0f / (float)n;
        float mean = s * inv_n;
        float var = fmaxf(qq * inv_n - mean * mean, 0.f);
        stg[y * 512 + c] = mean;
        stg[y * 512 + 256 + c] = rsqrtf(var + EPSV);
    }
}
// vectorized: 8 values per thread (uint4 in / uint4 out)
__global__ void bn_apply2_k(const u16* __restrict__ x, const float* __restrict__ stg,
                            const float* __restrict__ prm, u16* __restrict__ out, int n) {
    int y = blockIdx.y;
    int t = blockIdx.x * 256 + threadIdx.x;
    if (t >= n * (NF / 8)) return;
    int c = (t & 31) * 8;
    const float* st = stg + y * 512;
    const float* g = prm + (y ? P_AGG1 : P_G1);
    const float* be = prm + (y ? P_AGBE1 : P_BE1);
    uint4 u = *(const uint4*)(x + (size_t)y * n * NF + (size_t)t * 8);
    float v[8];
    v[0] = __uint_as_float(u.x << 16); v[1] = __uint_as_float(u.x & 0xFFFF0000u);
    v[2] = __uint_as_float(u.y << 16); v[3] = __uint_as_float(u.y & 0xFFFF0000u);
    v[4] = __uint_as_float(u.z << 16); v[5] = __uint_as_float(u.z & 0xFFFF0000u);
    v[6] = __uint_as_float(u.w << 16); v[7] = __uint_as_float(u.w & 0xFFFF0000u);
    float r[8];
#pragma unroll
    for (int k = 0; k < 8; ++k) {
        int cc = c + k;
        float w = (v[k] - st[cc]) * st[256 + cc] * g[cc] + be[cc];
        r[k] = fmaxf(w, 0.f);
    }
    st8h(out + (size_t)y * n * NF + (size_t)t * 8, r);
}

// ---------------- single-pass fused GAT aggregation via CSR ----------------
// half-wave per edge, 4-edge unroll; es gathers issued alongside row loads.
__global__ __launch_bounds__(256) void gat_csr_k(const u16* __restrict__ h,
                                                 const int* __restrict__ rp,
                                                 const int* __restrict__ col,
                                                 const float* __restrict__ es,
                                                 const float* __restrict__ ed,
                                                 const float* __restrict__ b,
                                                 u16* __restrict__ out, int n,
                                                 int do_relu) {
    int wave = threadIdx.x >> 6, lane = threadIdx.x & 63;
    int half = lane >> 5, sl = lane & 31;
    int i = blockIdx.x * 4 + wave;
    if (i >= n) return;
    int beg = rp[i], end = rp[i + 1];
    float edi = ed[i];
    int c = sl * 8;
    float acc[8] = {0.f, 0.f, 0.f, 0.f, 0.f, 0.f, 0.f, 0.f};
    float ws = __expf(lrelu(es[i] + edi));
    float selfw = half ? 0.f : ws;
    float ssum = selfw;
    uint4 uv = *(const uint4*)(h + (size_t)i * NF + c);
    fma8(uv, selfw, acc);
    int j = beg + half;
    for (; j + 6 < end; j += 8) {
        int s0 = col[j], s1 = col[j + 2], s2 = col[j + 4], s3 = col[j + 6];
        float e0 = es[s0], e1 = es[s1], e2 = es[s2], e3 = es[s3];
        uint4 u0 = *(const uint4*)(h + (size_t)s0 * NF + c);
        uint4 u1 = *(const uint4*)(h + (size_t)s1 * NF + c);
        uint4 u2 = *(const uint4*)(h + (size_t)s2 * NF + c);
        uint4 u3 = *(const uint4*)(h + (size_t)s3 * NF + c);
        float a0 = __expf(lrelu(e0 + edi));
        float a1 = __expf(lrelu(e1 + edi));
        float a2 = __expf(lrelu(e2 + edi));
        float a3 = __expf(lrelu(e3 + edi));
        ssum += (a0 + a1) + (a2 + a3);
        fma8(u0, a0, acc);
        fma8(u1, a1, acc);
        fma8(u2, a2, acc);
        fma8(u3, a3, acc);
    }
    for (; j < end; j += 2) {
        int s = col[j];
        float a = __expf(lrelu(es[s] + edi));
        uint4 u = *(const uint4*)(h + (size_t)s * NF + c);
        ssum += a;
        fma8(u, a, acc);
    }
    ssum += __shfl_xor(ssum, 32, 64);
#pragma unroll
    for (int k = 0; k < 8; ++k) acc[k] += __shfl_xor(acc[k], 32, 64);
    float inv = 1.0f / ssum;
#pragma unroll
    for (int k = 0; k < 8; ++k) {
        acc[k] = b[c + k] + acc[k] * inv;
        if (do_relu) acc[k] = fmaxf(acc[k], 0.f);
    }
    if (half == 0) st8h(out + (size_t)i * NF + c, acc);
}

// ---------------- batched final-stage BN stats over cat(x,h) (512 ch) ----------------
__global__ void bn_stats_cat2_k(const u16* __restrict__ xp, const u16* __restrict__ hp,
                                int n, float* __restrict__ psum, float* __restrict__ psq) {
    int y = blockIdx.y;
    int c = threadIdx.x;  // 512
    int r0 = blockIdx.x * 128;
    int rend = min(r0 + 128, n);
    const u16* src = ((c < 256) ? xp : hp) + (size_t)y * n * NF;
    int cc = c & 255;
    float s = 0.f, qq = 0.f;
    for (int r = r0; r < rend; ++r) {
        float v = bf2f(src[(size_t)r * NF + cc]);
        s += v; qq += v * v;
    }
    size_t o = (size_t)(y * PB + blockIdx.x) * 512 + c;
    psum[o] = s; psq[o] = qq;
}
// wave-per-channel finalize (512 channels)
__global__ void bn_fin_cat2_k(const float* __restrict__ psum, const float* __restrict__ psq,
                              float* __restrict__ stc, int n, int nb) {
    int y = blockIdx.y;
    int wave = threadIdx.x >> 6, lane = threadIdx.x & 63;
    int c = blockIdx.x * 4 + wave;   // 512 channels, grid.x = 128
    float s = 0.f, qq = 0.f;
    for (int b = lane; b < nb; b += 64) {
        size_t o = (size_t)(y * PB + b) * 512 + c;
        s += psum[o]; qq += psq[o];
    }
    s = wredsum(s);
    qq = wredsum(qq);
    if (lane == 0) {
        float inv_n = 1.0f / (float)n;
        float mean = s * inv_n;
        float var = fmaxf(qq * inv_n - mean * mean, 0.f);
        stc[y * 1024 + c] = mean;
        stc[y * 1024 + 512 + c] = rsqrtf(var + EPSV);
    }
}
__global__ void final2_k(const u16* __restrict__ xp, const u16* __restrict__ hp,
                         const float* __restrict__ stc, const float* __restrict__ prm,
                         float* __restrict__ out, int n) {
    int y = blockIdx.y;
    int wave = threadIdx.x >> 6, lane = threadIdx.x & 63;
    int i = blockIdx.x * 4 + wave;
    if (i >= n) return;
    const float* st = stc + y * 1024;
    const float* g = prm + (y ? P_AGG2 : P_G2);
    const float* be = prm + (y ? P_AGBE2 : P_BE2);
    const float* w = prm + (y ? P_WAGFC : P_WFC);
    float bias = prm[y ? P_BAGFC : P_BFC];
    const u16* src = (((lane < 32) ? xp : hp) + (size_t)y * n * NF) + (size_t)i * NF
                     + (lane < 32 ? lane * 8 : (lane - 32) * 8);
    uint4 u = *(const uint4*)src;
    float vv[8];
    vv[0] = bf2f((u16)(u.x & 0xFFFFu)); vv[1] = bf2f((u16)(u.x >> 16));
    vv[2] = bf2f((u16)(u.y & 0xFFFFu)); vv[3] = bf2f((u16)(u.y >> 16));
    vv[4] = bf2f((u16)(u.z & 0xFFFFu)); vv[5] = bf2f((u16)(u.z >> 16));
    vv[6] = bf2f((u16)(u.w & 0xFFFFu)); vv[7] = bf2f((u16)(u.w >> 16));
    int c0 = lane * 8;
    float acc = 0.f;
#pragma unroll
    for (int j = 0; j < 8; ++j) {
        int c = c0 + j;
        float v = (vv[j] - st[c]) * st[512 + c] * g[c] + be[c];
        v = fmaxf(v, 0.f);
        acc += v * w[c];
    }
    acc = wredsum(acc);
    if (lane == 0) out[(size_t)y * 20000 + i] = acc + bias;
}

// ---------------- host ----------------
extern "C" void kernel_launch(void* const* d_in, const int* in_sizes, int n_in,
                              void* d_out, int out_size, void* d_ws, size_t ws_size,
                              hipStream_t stream) {
    const void* x_ab = d_in[0];
    const void* x_ag = d_in[1];
    const int* e_ab = (const int*)d_in[26];
    const int* e_ag = (const int*)d_in[27];
    const int* e_d = (const int*)d_in[28];

    const int NAB = 20000, NT = 40000;
    const int EAB = 320000, EAG = 320000, ED = 640000;

    u16* hcat = (u16*)d_ws;                     // NT*NF u16
    u16* bufA = hcat + (size_t)NT * NF;         // NT*NF u16
    u16* bufB = bufA + (size_t)NT * NF;         // NT*NF u16
    u16* wt4 = bufB + (size_t)NT * NF;          // 4*65536 u16
    float* dv0 = (float*)(wt4 + 4 * 65536);     // NAB
    float* dv1 = dv0 + NAB;                     // NAB
    float* es = dv1 + NAB;                      // NT
    float* edv = es + NT;                       // NT
    float* stg2 = edv + NT;                     // 1024
    float* stc = stg2 + 1024;                   // 2048
    float* psum = stc + 2048;                   // 2*PB*512
    float* psq = psum + 2 * PB * 512;           // 2*PB*512
    float* prm = psq + 2 * PB * 512;            // 8192
    int* flag = (int*)(prm + 8192);             // 16
    int* rp_ab = flag + 16;                     // NAB+1
    int* rp_ag = rp_ab + NAB + 1;               // NAB+1
    int* rp_d = rp_ag + NAB + 1;                // NT+1
    int* gbcnt = rp_d + NT + 1;                 // 3*MAXBUK
    int* gcur = gbcnt + 3 * MAXBUK;             // 3*MAXBUK
    int* bb = gcur + 3 * MAXBUK;                // 3*(MAXBUK+1)
    int* col_ab = bb + 3 * (MAXBUK + 1);        // EAB
    int* col_ag = col_ab + EAB;                 // EAG
    int* col_d = col_ag + EAG;                  // ED
    u32* stg_ab = (u32*)(col_d + ED);           // EAB
    u32* stg_ag = stg_ab + EAB;                 // EAG
    u32* stg_d = stg_ag + EAG;                  // ED

    u16* wt_gcn = wt4;
    u16* wt_aggcn = wt4 + 65536;
    u16* wt_gat = wt4 + 2 * 65536;
    u16* wt_gat2 = wt4 + 3 * 65536;

    dim3 t256(256), t512(512);
    const int nbg = (NAB + 127) / 128;   // 157 bn partial blocks per graph

    detect_k<<<dim3(1), t256, 0, stream>>>((const u16*)x_ab, flag);
    prep_k<<<dim3(1049), t256, 0, stream>>>(
        d_in[2], d_in[6], d_in[10], d_in[14],
        d_in[3], d_in[4], d_in[5], d_in[7], d_in[8], d_in[9],
        d_in[11], d_in[12], d_in[13], d_in[15], d_in[16], d_in[17],
        d_in[22], d_in[23], d_in[24], d_in[18], d_in[19], d_in[20],
        d_in[25], d_in[21], wt4, prm, gbcnt, 6 * MAXBUK + 3 * (MAXBUK + 1), flag);

    // bucket-level CSR build (4 dispatches)
    bucket_cnt3_k<<<dim3(157, 3), t256, 0, stream>>>(e_ab, e_ag, e_d, gbcnt);
    bucket_scan3_k<<<dim3(1, 3), t256, 0, stream>>>(gbcnt, bb, rp_ab, rp_ag, rp_d);
    bin3_k<<<dim3(157, 3), t256, 0, stream>>>(e_ab, e_ag, e_d, bb, gcur,
                                              stg_ab, stg_ag, stg_d);
    place3_k<<<dim3(157, 3), t256, 0, stream>>>(stg_ab, stg_ag, stg_d, bb,
                                                rp_ab, rp_ag, rp_d, dv0, dv1,
                                                col_ab, col_ag, col_d);

    // batched GCN stage (5 dispatches)
    gemm2_k<<<dim3((NAB + 63) / 64, 2), t256, 0, stream>>>(x_ab, x_ag, wt_gcn, wt_aggcn,
                                                           flag, bufA, NAB);
    gcn_csr2_k<<<dim3((NAB + 3) / 4, 2), t256, 0, stream>>>(bufA, rp_ab, rp_ag,
                                                            col_ab, col_ag, dv0, dv1,
                                                            prm, bufB, NAB);
    bn_stats2_k<<<dim3(nbg, 2), t256, 0, stream>>>(bufB, NAB, psum, psq);
    bn_fin2_k<<<dim3(64, 2), t256, 0, stream>>>(psum, psq, stg2, NAB, nbg);
    bn_apply2_k<<<dim3((NAB * NF / 8 + 255) / 256, 2), t256, 0, stream>>>(bufB, stg2, prm,
                                                                          hcat, NAB);

    // GAT layer 1 (2 dispatches)
    gemm_gat_k<<<dim3((NT + 63) / 64), t256, 0, stream>>>(hcat, wt_gat, bufA, NT,
                                                          prm + P_ASRC, prm + P_ADST,
                                                          es, edv);
    gat_csr_k<<<dim3((NT + 3) / 4), t256, 0, stream>>>(bufA, rp_d, col_d, es, edv,
                                                       prm + P_BGAT, bufB, NT, 1);
    // GAT layer 2 (2 dispatches)
    gemm_gat_k<<<dim3((NT + 63) / 64), t256, 0, stream>>>(bufB, wt_gat2, bufA, NT,
                                                          prm + P_ASRC2, prm + P_ADST2,
                                                          es, edv);
    gat_csr_k<<<dim3((NT + 3) / 4), t256, 0, stream>>>(bufA, rp_d, col_d, es, edv,
                                                       prm + P_BGAT2, bufB, NT, 0);

    // batched final stage (3 dispatches)
    bn_stats_cat2_k<<<dim3(nbg, 2), t512, 0, stream>>>(bufB, hcat, NAB, psum, psq);
    bn_fin_cat2_k<<<dim3(128, 2), t256, 0, stream>>>(psum, psq, stc, NAB, nbg);
    final2_k<<<dim3((NAB + 3) / 4, 2), t256, 0, stream>>>(bufB, hcat, stc, prm,
                                                          (float*)d_out, NAB);
}